// Round 6
// baseline (8457.240 us; speedup 1.0000x reference)
//
#include <hip/hip_runtime.h>
#include <math.h>

#define BB 32
#define TT 64
#define NNODES 256
#define FDIM 64
#define SLICE (NNODES*FDIM)          // 16384 floats per (b,t) slice
#define NTOT (BB*TT*NNODES*FDIM)     // 33554432
#define RANK0 838860u                // ascending order-statistic index: T*N*F - k - 1, k=209715

typedef float v2f __attribute__((ext_vector_type(2)));
__device__ __forceinline__ v2f pkfma(v2f a, v2f b, v2f c) {
#if __has_builtin(__builtin_elementwise_fma)
  return __builtin_elementwise_fma(a, b, c);
#else
  v2f r; r.x = fmaf(a.x,b.x,c.x); r.y = fmaf(a.y,b.y,c.y); return r;
#endif
}
__device__ __forceinline__ float za_get(const v2f* a, int o) {
  return (o & 1) ? a[o>>1].y : a[o>>1].x;
}

// ---------------- weight combine: 7 effective taps (-3..+3) ----------------
__global__ __launch_bounds__(256) void combine_w(
    const float* __restrict__ Wc1, const float* __restrict__ bc1,
    const float* __restrict__ Wc2, const float* __restrict__ bc2,
    const float* __restrict__ Wc3, const float* __restrict__ bc3,
    float* __restrict__ Wcomb, float* __restrict__ bcomb)
{
  const int FF2 = FDIM*FDIM;
  int gid = blockIdx.x*256 + threadIdx.x;
  if (gid < 7*FF2) {
    int j = gid / FF2, r = gid % FF2;
    float v;
    switch (j) {
      case 0: v = Wc3[r]; break;                                   // offset -3
      case 1: v = Wc2[r]; break;                                   // offset -2
      case 2: v = Wc1[r]; break;                                   // offset -1
      case 3: v = Wc1[FF2+r] + Wc2[FF2+r] + Wc3[FF2+r]; break;     // offset  0
      case 4: v = Wc1[2*FF2+r]; break;                             // offset +1
      case 5: v = Wc2[2*FF2+r]; break;                             // offset +2
      default: v = Wc3[2*FF2+r]; break;                            // offset +3
    }
    Wcomb[gid] = v;
  }
  if (gid < FDIM) bcomb[gid] = bc1[gid] + bc2[gid] + bc3[gid];
}

// ---------------- fold Q/K projections: Wqk = Wq*Wk^T, zb = bq*Wk^T ----------------
__global__ __launch_bounds__(256) void combine_qk(
    const float* __restrict__ Wq, const float* __restrict__ bq,
    const float* __restrict__ Wk,
    float* __restrict__ Wqk, float* __restrict__ zb)
{
  int gid = blockIdx.x*256 + threadIdx.x;
  if (gid < 4096) {
    int i = gid >> 6, j = gid & 63;
    float a = 0.f;
    for (int o=0;o<64;o++) a = fmaf(Wq[i*64+o], Wk[j*64+o], a);
    Wqk[i*64+j] = a;
  } else if (gid < 4160) {
    int j = gid - 4096;
    float a = 0.f;
    for (int o=0;o<64;o++) a = fmaf(bq[o], Wk[j*64+o], a);
    zb[j] = a;
  }
}

// ---------------- dilated conv block + residual, per (b,n) slice ----------------
__global__ __launch_bounds__(256,4) void conv_kernel(
    const float* __restrict__ x, const float* __restrict__ Wcomb,
    const float* __restrict__ bcomb, float* __restrict__ x1)
{
  __shared__ float xs[64*72];        // [f][t+4], t in [-4,68), zero-padded
  const int bn = blockIdx.x; const int b = bn >> 8; const int n = bn & 255;
  const int tid = threadIdx.x;
#pragma unroll
  for (int k=0;k<18;k++) xs[k*256+tid] = 0.f;
  __syncthreads();
  const float* xbase = x + ((size_t)b*TT)*SLICE + n*FDIM;
#pragma unroll
  for (int it=0; it<4; it++) {
    int flat4 = it*256 + tid;
    int t = flat4 >> 4, f4 = (flat4 & 15) << 2;
    float4 v = *(const float4*)(xbase + (size_t)t*SLICE + f4);
    xs[(f4+0)*72 + t+4] = v.x;
    xs[(f4+1)*72 + t+4] = v.y;
    xs[(f4+2)*72 + t+4] = v.z;
    xs[(f4+3)*72 + t+4] = v.w;
  }
  __syncthreads();
  const int o = tid & 63;            // lane -> output feature
  const int tb = (tid >> 6) << 4;    // wave -> 16-step t range (wave-uniform)
  float acc[16];
  const float bco = bcomb[o];
#pragma unroll
  for (int k=0;k<16;k++) acc[k] = bco;
  for (int i=0;i<FDIM;i++) {
    float xr[24];
#pragma unroll
    for (int q=0;q<6;q++) {
      float4 v = *(const float4*)&xs[i*72 + tb + q*4];
      xr[q*4+0]=v.x; xr[q*4+1]=v.y; xr[q*4+2]=v.z; xr[q*4+3]=v.w;
    }
#pragma unroll
    for (int j=0;j<7;j++) {
      float w = Wcomb[(j*FDIM+i)*FDIM + o];
#pragma unroll
      for (int k=0;k<16;k++) acc[k] = fmaf(xr[k+j+1], w, acc[k]);
    }
  }
  float* obase = x1 + ((size_t)b*TT)*SLICE + n*FDIM + o;
#pragma unroll
  for (int k=0;k<16;k++) {
    int t = tb + k;
    float c = acc[k];
    float outv = xs[o*72 + t+4] + (c > 0.f ? c : 0.f);
    obase[(size_t)t*SLICE] = outv;
  }
}

// ---------------- attention (diag softmax) + dense + inf-norm, per (b,t) ----------------
// 512 threads, 1 block/CU. LDS: x[256][68] + z[256][68] + exchange (4KB).
// Scores: wave w -> n-band nb=w&3 (64 n), m-half mh=w>>2 (128 m). Lane l=(li<<3)|lj:
// 8n x 4m register tile, n = 64nb+li+8ii, m = 128mh+32mt+lj+8jj. Per k-chunk 12
// conflict-free ds_read_b128 (per-instruction lanes hit consecutive rows; stride 68
// => 4-bank steps cover all 32 banks) with compile-time offsets, feeding 64 pkfma.
// S/diag reduced over lj (shfl_xor 1/2/4), cross-wave m-halves via LDS exchange.
// Epilogue (V/dense/norm) split across thread-halves h with LDS o1/nrm exchange.
__global__ __launch_bounds__(512,1) void attn_kernel(
    const float* __restrict__ x1,
    const float* __restrict__ Wqk, const float* __restrict__ zb,
    const float* __restrict__ Wv, const float* __restrict__ bv,
    const float* __restrict__ Wd, const float* __restrict__ bd,
    float* __restrict__ vout)
{
  __shared__ float lds[2*256*68 + 1024];
  float* xs  = lds;                  // [256][68] x rows
  float* zs  = lds + 256*68;         // [256][68] z rows -> o1buf -> vbuf
  float* exS = lds + 2*256*68;       // [2][256] softmax denom halves; later nrm halves
  float* exD = exS + 512;            // [2][256] diag halves
  const int bt  = blockIdx.x;
  const int tid = threadIdx.x;
  const int w = tid >> 6, l = tid & 63;
  const int nb = w & 3, mh = w >> 2;
  const int li = l >> 3, lj = l & 7;
  const float* xsl = x1 + (size_t)bt*SLICE;

  // ---- stage-in x ----
  const float4* xb4 = (const float4*)xsl;
#pragma unroll
  for (int it=0; it<8; it++) {
    int flat4 = it*512 + tid;
    int row = flat4 >> 4, c = flat4 & 15;
    *(float4*)&xs[row*68 + c*4] = xb4[flat4];
  }
  __syncthreads();

  // ---- z-projection: thread (n = tid&255, h = tid>>8) computes z[n][32h..+32) ----
  const int n  = tid & 255;
  const int h  = tid >> 8;
  const int col0 = 32 * h;
  {
    float xr0[64];
#pragma unroll
    for (int q=0;q<16;q++) {
      float4 v = *(const float4*)&xs[n*68 + 4*q];
      xr0[4*q]=v.x; xr0[4*q+1]=v.y; xr0[4*q+2]=v.z; xr0[4*q+3]=v.w;
    }
    v2f za[16];
#pragma unroll
    for (int j=0;j<16;j++) { v2f t; t.x = zb[col0+2*j]; t.y = zb[col0+2*j+1]; za[j] = t; }
    for (int i=0;i<64;i++) {
      v2f xv; xv.x = xr0[i]; xv.y = xr0[i];
      const float4* wr = (const float4*)(Wqk + i*64 + col0);
#pragma unroll
      for (int qq=0;qq<8;qq++) {
        float4 w4 = wr[qq];
        v2f wlo; wlo.x=w4.x; wlo.y=w4.y;
        v2f whi; whi.x=w4.z; whi.y=w4.w;
        za[2*qq]   = pkfma(xv, wlo, za[2*qq]);
        za[2*qq+1] = pkfma(xv, whi, za[2*qq+1]);
      }
    }
#pragma unroll
    for (int qq=0;qq<8;qq++) {
      float4 t; t.x=za[2*qq].x; t.y=za[2*qq].y; t.z=za[2*qq+1].x; t.w=za[2*qq+1].y;
      *(float4*)&zs[n*68 + col0 + 4*qq] = t;
    }
  }
  __syncthreads();

  // ---- score phase ----
  float S[8] = {0,0,0,0,0,0,0,0};
  float D[8] = {0,0,0,0,0,0,0,0};
  const float* zrow = &zs[(64*nb + li)*68];
#pragma unroll
  for (int mt=0; mt<4; mt++) {
    const float* xrow = &xs[(128*mh + 32*mt + lj)*68];
    v2f acc[8][4];
#pragma unroll
    for (int ii=0;ii<8;ii++)
#pragma unroll
      for (int jj=0;jj<4;jj++) { acc[ii][jj].x = 0.f; acc[ii][jj].y = 0.f; }
#pragma unroll
    for (int kc=0; kc<16; kc++) {
      float4 z4[8];
#pragma unroll
      for (int ii=0;ii<8;ii++) z4[ii] = *(const float4*)(zrow + ii*(8*68) + kc*4);
      float4 x4[4];
#pragma unroll
      for (int jj=0;jj<4;jj++) x4[jj] = *(const float4*)(xrow + jj*(8*68) + kc*4);
#pragma unroll
      for (int ii=0;ii<8;ii++) {
        v2f zlo; zlo.x=z4[ii].x; zlo.y=z4[ii].y;
        v2f zhi; zhi.x=z4[ii].z; zhi.y=z4[ii].w;
#pragma unroll
        for (int jj=0;jj<4;jj++) {
          v2f xlo; xlo.x=x4[jj].x; xlo.y=x4[jj].y;
          v2f xhi; xhi.x=x4[jj].z; xhi.y=x4[jj].w;
          acc[ii][jj] = pkfma(zlo, xlo, acc[ii][jj]);
          acc[ii][jj] = pkfma(zhi, xhi, acc[ii][jj]);
        }
      }
    }
#pragma unroll
    for (int ii=0;ii<8;ii++) {
#pragma unroll
      for (int jj=0;jj<4;jj++) {
        float s = (acc[ii][jj].x + acc[ii][jj].y) * 0.125f;
        int m  = 128*mh + 32*mt + 8*jj + lj;
        int nn = 64*nb + 8*ii + li;
        if (m == nn) D[ii] = s;
        S[ii] += __expf(s);
      }
    }
  }
#pragma unroll
  for (int d=1; d<8; d<<=1) {
#pragma unroll
    for (int ii=0;ii<8;ii++) {
      S[ii] += __shfl_xor(S[ii], d);
      D[ii] += __shfl_xor(D[ii], d);
    }
  }
  {
    int nn = 64*nb + li + 8*lj;
    exS[mh*256 + nn] = S[lj];
    exD[mh*256 + nn] = D[lj];
  }
  __syncthreads();

  // ---- epilogue: thread (n, h) ----
  const float Ssum = exS[n] + exS[256 + n];
  const float Dsum = exD[n] + exD[256 + n];
  const float ann = __expf(Dsum) / Ssum;

  float xr[64];
#pragma unroll
  for (int q=0;q<16;q++) {
    float4 v = *(const float4*)&xs[n*68 + 4*q];
    xr[4*q]=v.x; xr[4*q+1]=v.y; xr[4*q+2]=v.z; xr[4*q+3]=v.w;
  }
  {
    v2f va[16];
#pragma unroll
    for (int j=0;j<16;j++) { v2f t; t.x = bv[col0+2*j]; t.y = bv[col0+2*j+1]; va[j] = t; }
    for (int i=0;i<64;i++) {
      v2f xv; xv.x = xr[i]; xv.y = xr[i];
      const float4* wr = (const float4*)(Wv + i*64 + col0);
#pragma unroll
      for (int qq=0;qq<8;qq++) {
        float4 w4 = wr[qq];
        v2f wlo; wlo.x=w4.x; wlo.y=w4.y;
        v2f whi; whi.x=w4.z; whi.y=w4.w;
        va[2*qq]   = pkfma(xv, wlo, va[2*qq]);
        va[2*qq+1] = pkfma(xv, whi, va[2*qq+1]);
      }
    }
#pragma unroll
    for (int qq=0;qq<8;qq++) {
      float g0 = ann * za_get(va, 4*qq+0);
      float g1 = ann * za_get(va, 4*qq+1);
      float g2 = ann * za_get(va, 4*qq+2);
      float g3 = ann * za_get(va, 4*qq+3);
      float4 t;
      t.x = xr[col0+4*qq+0] + (g0 > 0.f ? g0 : 0.f);
      t.y = xr[col0+4*qq+1] + (g1 > 0.f ? g1 : 0.f);
      t.z = xr[col0+4*qq+2] + (g2 > 0.f ? g2 : 0.f);
      t.w = xr[col0+4*qq+3] + (g3 > 0.f ? g3 : 0.f);
      *(float4*)&zs[n*68 + col0 + 4*qq] = t;   // z dead; o1 own half
    }
  }
  __syncthreads();
  float dd[32];
  {
    float o1[64];
#pragma unroll
    for (int q=0;q<16;q++) {
      float4 v = *(const float4*)&zs[n*68 + 4*q];
      o1[4*q]=v.x; o1[4*q+1]=v.y; o1[4*q+2]=v.z; o1[4*q+3]=v.w;
    }
    v2f da[16];
#pragma unroll
    for (int j=0;j<16;j++) { v2f t; t.x = bd[col0+2*j]; t.y = bd[col0+2*j+1]; da[j] = t; }
    for (int i=0;i<64;i++) {
      v2f xv; xv.x = o1[i]; xv.y = o1[i];
      const float4* wr = (const float4*)(Wd + i*64 + col0);
#pragma unroll
      for (int qq=0;qq<8;qq++) {
        float4 w4 = wr[qq];
        v2f wlo; wlo.x=w4.x; wlo.y=w4.y;
        v2f whi; whi.x=w4.z; whi.y=w4.w;
        da[2*qq]   = pkfma(xv, wlo, da[2*qq]);
        da[2*qq+1] = pkfma(xv, whi, da[2*qq+1]);
      }
    }
#pragma unroll
    for (int o=0;o<32;o++) dd[o] = za_get(da, o);
  }
  float nh = 0.f;
#pragma unroll
  for (int o=0;o<32;o++) nh = fmaxf(nh, fabsf(dd[o]));
  exS[h*256 + n] = nh;               // exS reuse: Ssum reads all happened pre-barrier
  __syncthreads();
  const float nrm = fmaxf(exS[n], exS[256 + n]);
#pragma unroll
  for (int qq=0;qq<8;qq++) {
    float4 t;
    t.x = 0.5f*(dd[4*qq+0]/nrm + 1.f);
    t.y = 0.5f*(dd[4*qq+1]/nrm + 1.f);
    t.z = 0.5f*(dd[4*qq+2]/nrm + 1.f);
    t.w = 0.5f*(dd[4*qq+3]/nrm + 1.f);
    *(float4*)&zs[n*68 + col0 + 4*qq] = t;   // o1 fully consumed pre-barrier
  }
  __syncthreads();
  float4* ob4 = (float4*)(vout + (size_t)bt*SLICE);
#pragma unroll
  for (int it=0; it<8; it++) {
    int flat4 = it*512 + tid;
    int row = flat4 >> 4, c = flat4 & 15;
    ob4[flat4] = *(const float4*)&zs[row*68 + c*4];
  }
}

// ---------------- radix-select histograms (values are non-negative floats) ----------------
template<int LEVEL>
__global__ __launch_bounds__(256) void hist_kernel(
    const float* __restrict__ v, unsigned* __restrict__ ghist,
    const unsigned* __restrict__ pfx)
{
  __shared__ unsigned hh[4096];
  const int batch = blockIdx.x >> 5, chunk = blockIdx.x & 31;
  const int tid = threadIdx.x;
#pragma unroll
  for (int k=0;k<16;k++) hh[k*256+tid] = 0u;
  __syncthreads();
  const unsigned p = pfx ? pfx[batch] : 0u;
  const float4* vb = (const float4*)(v + (size_t)batch*(TT*SLICE)) + chunk*8192 + tid;
  for (int k=0;k<32;k++) {
    float4 q = vb[k*256];
    float e[4] = {q.x,q.y,q.z,q.w};
#pragma unroll
    for (int j=0;j<4;j++) {
      unsigned u = __float_as_uint(e[j]);
      if (LEVEL==1) atomicAdd(&hh[u>>20], 1u);
      else if ((u>>20)==p) atomicAdd(&hh[(u>>8)&0xFFFu], 1u);
    }
  }
  __syncthreads();
  unsigned* gh = ghist + batch*4096;
#pragma unroll
  for (int k=0;k<16;k++) { unsigned c = hh[k*256+tid]; if (c) atomicAdd(&gh[k*256+tid], c); }
}

__global__ __launch_bounds__(256) void hist8_kernel(
    const float* __restrict__ v, unsigned* __restrict__ ghist,
    const unsigned* __restrict__ pfx)
{
  __shared__ unsigned hh[256];
  const int batch = blockIdx.x >> 5, chunk = blockIdx.x & 31;
  const int tid = threadIdx.x;
  hh[tid] = 0u;
  __syncthreads();
  const unsigned p = pfx[batch];
  const float4* vb = (const float4*)(v + (size_t)batch*(TT*SLICE)) + chunk*8192 + tid;
  for (int k=0;k<32;k++) {
    float4 q = vb[k*256];
    float e[4] = {q.x,q.y,q.z,q.w};
#pragma unroll
    for (int j=0;j<4;j++) {
      unsigned u = __float_as_uint(e[j]);
      if ((u>>8)==p) atomicAdd(&hh[u & 255u], 1u);
    }
  }
  __syncthreads();
  unsigned c = hh[tid];
  if (c) atomicAdd(&ghist[batch*256+tid], c);
}

// ---------------- find bin containing the rank (block scan per batch) ----------------
template<int PER>
__global__ __launch_bounds__(256) void find_kernel(
    const unsigned* __restrict__ hist,
    const unsigned* __restrict__ rank_in, const unsigned* __restrict__ pfx_in,
    int pfx_shift, unsigned* __restrict__ pfx_out, unsigned* __restrict__ rank_out,
    float* __restrict__ mu, int final_level)
{
  __shared__ unsigned csum[256];
  const int batch = blockIdx.x;
  const int tid = threadIdx.x;
  const unsigned* hb = hist + batch*(PER*256);
  unsigned loc[PER];
  unsigned s = 0;
#pragma unroll
  for (int q=0;q<PER;q++) { loc[q] = hb[tid*PER+q]; s += loc[q]; }
  csum[tid] = s;
  __syncthreads();
  for (int off=1; off<256; off<<=1) {
    unsigned vv = csum[tid];
    unsigned ad = (tid >= off) ? csum[tid-off] : 0u;
    __syncthreads();
    csum[tid] = vv + ad;
    __syncthreads();
  }
  const unsigned rank = rank_in ? rank_in[batch] : RANK0;
  const unsigned excl = csum[tid] - s;
  if (rank >= excl && rank < excl + s) {
    unsigned r = rank - excl;
    int bin = 0;
#pragma unroll
    for (int q=0;q<PER;q++) {
      if (r < loc[q]) { bin = tid*PER + q; break; }
      r -= loc[q];
    }
    unsigned pf = pfx_in ? pfx_in[batch] : 0u;
    unsigned np = (pf << pfx_shift) | (unsigned)bin;
    if (final_level) { mu[batch] = __uint_as_float(np); }
    else { pfx_out[batch] = np; rank_out[batch] = r; }
  }
}

// ---------------- sigmoid + STE mask + predictor, per (b,t) ----------------
__global__ __launch_bounds__(256,2) void final_kernel(
    const float* __restrict__ v, const float* __restrict__ mu,
    const float* __restrict__ Wp, const float* __restrict__ bp,
    float* __restrict__ pred, float* __restrict__ mask)
{
  __shared__ float sl[NNODES*68];
  const int bt = blockIdx.x;
  const int b = bt >> 6;
  const int tid = threadIdx.x;
  const float4* vb4 = (const float4*)(v + (size_t)bt*SLICE);
#pragma unroll
  for (int it=0; it<16; it++) {
    int flat4 = it*256 + tid;
    int n = flat4 >> 4, f4 = (flat4 & 15) << 2;
    *(float4*)&sl[n*68 + f4] = vb4[flat4];
  }
  __syncthreads();
  const float muv = mu[b];
  float srow[64];
#pragma unroll
  for (int q=0;q<16;q++) {
    float4 vv = *(const float4*)&sl[tid*68 + q*4];
    float e0 = 1.f/(1.f + expf(-(vv.x - muv)));
    float e1 = 1.f/(1.f + expf(-(vv.y - muv)));
    float e2 = 1.f/(1.f + expf(-(vv.z - muv)));
    float e3 = 1.f/(1.f + expf(-(vv.w - muv)));
    float m0 = rintf(e0), m1 = rintf(e1), m2 = rintf(e2), m3 = rintf(e3);
    srow[q*4+0] = e0*m0; srow[q*4+1] = e1*m1; srow[q*4+2] = e2*m2; srow[q*4+3] = e3*m3;
    float4 w; w.x=m0; w.y=m1; w.z=m2; w.w=m3;
    *(float4*)&sl[tid*68 + q*4] = w;
  }
  __syncthreads();
  float4* mb4 = (float4*)(mask + (size_t)bt*SLICE);
#pragma unroll
  for (int it=0; it<16; it++) {
    int flat4 = it*256 + tid;
    int n = flat4 >> 4, f4 = (flat4 & 15) << 2;
    mb4[flat4] = *(const float4*)&sl[n*68 + f4];
  }
  float acc[64];
#pragma unroll
  for (int o=0;o<64;o++) acc[o]=0.f;
  for (int i=0;i<64;i++) {
    float sv = srow[i];
#pragma unroll
    for (int o=0;o<64;o++) acc[o] = fmaf(sv, Wp[i*64+o], acc[o]);
  }
  __syncthreads();
#pragma unroll
  for (int q=0;q<16;q++) {
    float4 w;
    w.x = acc[q*4+0]+bp[q*4+0]; w.y = acc[q*4+1]+bp[q*4+1];
    w.z = acc[q*4+2]+bp[q*4+2]; w.w = acc[q*4+3]+bp[q*4+3];
    *(float4*)&sl[tid*68 + q*4] = w;
  }
  __syncthreads();
  float4* pb4 = (float4*)(pred + (size_t)bt*SLICE);
#pragma unroll
  for (int it=0; it<16; it++) {
    int flat4 = it*256 + tid;
    int n = flat4 >> 4, f4 = (flat4 & 15) << 2;
    pb4[flat4] = *(const float4*)&sl[n*68 + f4];
  }
}

extern "C" void kernel_launch(void* const* d_in, const int* in_sizes, int n_in,
                              void* d_out, int out_size, void* d_ws, size_t ws_size,
                              hipStream_t stream) {
  const float* x   = (const float*)d_in[0];
  const float* Wc1 = (const float*)d_in[1];  const float* bc1 = (const float*)d_in[2];
  const float* Wc2 = (const float*)d_in[3];  const float* bc2 = (const float*)d_in[4];
  const float* Wc3 = (const float*)d_in[5];  const float* bc3 = (const float*)d_in[6];
  const float* Wq  = (const float*)d_in[7];  const float* bq  = (const float*)d_in[8];
  const float* Wk  = (const float*)d_in[9];
  const float* Wv  = (const float*)d_in[11]; const float* bv  = (const float*)d_in[12];
  const float* Wd  = (const float*)d_in[13]; const float* bd  = (const float*)d_in[14];
  const float* Wp  = (const float*)d_in[15]; const float* bp  = (const float*)d_in[16];

  float* pred = (float*)d_out;       // also holds pre-sigmoid v, overwritten in place
  float* mask = pred + NTOT;         // also holds conv output x1, overwritten in place

  unsigned* hist1 = (unsigned*)d_ws;           // 32*4096
  unsigned* hist2 = hist1 + 32*4096;           // 32*4096
  unsigned* hist3 = hist2 + 32*4096;           // 32*256
  unsigned* pfx1  = hist3 + 32*256;
  unsigned* rank1 = pfx1 + 32;
  unsigned* pfx2  = rank1 + 32;
  unsigned* rank2 = pfx2 + 32;
  float*    muv   = (float*)(rank2 + 32);
  float*    Wcomb = muv + 32;                  // 7*64*64
  float*    bcomb = Wcomb + 7*64*64;           // 64
  float*    Wqk   = bcomb + 64;                // 64*64
  float*    zbv   = Wqk + 64*64;               // 64

  hipMemsetAsync(d_ws, 0, (size_t)(32*4096*2 + 32*256)*sizeof(unsigned), stream);
  combine_w<<<112, 256, 0, stream>>>(Wc1,bc1,Wc2,bc2,Wc3,bc3,Wcomb,bcomb);
  combine_qk<<<17, 256, 0, stream>>>(Wq,bq,Wk,Wqk,zbv);
  conv_kernel<<<BB*NNODES, 256, 0, stream>>>(x, Wcomb, bcomb, mask /*x1*/);
  attn_kernel<<<BB*TT, 512, 0, stream>>>(mask /*x1*/, Wqk,zbv, Wv,bv,Wd,bd, pred /*v*/);
  hist_kernel<1><<<1024, 256, 0, stream>>>(pred, hist1, nullptr);
  find_kernel<16><<<32, 256, 0, stream>>>(hist1, nullptr, nullptr, 0, pfx1, rank1, nullptr, 0);
  hist_kernel<2><<<1024, 256, 0, stream>>>(pred, hist2, pfx1);
  find_kernel<16><<<32, 256, 0, stream>>>(hist2, rank1, pfx1, 12, pfx2, rank2, nullptr, 0);
  hist8_kernel<<<1024, 256, 0, stream>>>(pred, hist3, pfx2);
  find_kernel<1><<<32, 256, 0, stream>>>(hist3, rank2, pfx2, 8, nullptr, nullptr, muv, 1);
  final_kernel<<<BB*TT, 256, 0, stream>>>(pred /*v*/, muv, Wp, bp, pred, mask);
}

// Round 7
// 1912.451 us; speedup vs baseline: 4.4222x; 4.4222x over previous
//
#include <hip/hip_runtime.h>
#include <math.h>

#define BB 32
#define TT 64
#define NNODES 256
#define FDIM 64
#define SLICE (NNODES*FDIM)          // 16384 floats per (b,t) slice
#define NTOT (BB*TT*NNODES*FDIM)     // 33554432
#define RANK0 838860u                // ascending order-statistic index: T*N*F - k - 1, k=209715

typedef float v2f __attribute__((ext_vector_type(2)));
__device__ __forceinline__ v2f pkfma(v2f a, v2f b, v2f c) {
#if __has_builtin(__builtin_elementwise_fma)
  return __builtin_elementwise_fma(a, b, c);
#else
  v2f r; r.x = fmaf(a.x,b.x,c.x); r.y = fmaf(a.y,b.y,c.y); return r;
#endif
}
__device__ __forceinline__ float za_get(const v2f* a, int o) {
  return (o & 1) ? a[o>>1].y : a[o>>1].x;
}

// ---------------- weight combine: 7 effective taps (-3..+3) ----------------
__global__ __launch_bounds__(256) void combine_w(
    const float* __restrict__ Wc1, const float* __restrict__ bc1,
    const float* __restrict__ Wc2, const float* __restrict__ bc2,
    const float* __restrict__ Wc3, const float* __restrict__ bc3,
    float* __restrict__ Wcomb, float* __restrict__ bcomb)
{
  const int FF2 = FDIM*FDIM;
  int gid = blockIdx.x*256 + threadIdx.x;
  if (gid < 7*FF2) {
    int j = gid / FF2, r = gid % FF2;
    float v;
    switch (j) {
      case 0: v = Wc3[r]; break;                                   // offset -3
      case 1: v = Wc2[r]; break;                                   // offset -2
      case 2: v = Wc1[r]; break;                                   // offset -1
      case 3: v = Wc1[FF2+r] + Wc2[FF2+r] + Wc3[FF2+r]; break;     // offset  0
      case 4: v = Wc1[2*FF2+r]; break;                             // offset +1
      case 5: v = Wc2[2*FF2+r]; break;                             // offset +2
      default: v = Wc3[2*FF2+r]; break;                            // offset +3
    }
    Wcomb[gid] = v;
  }
  if (gid < FDIM) bcomb[gid] = bc1[gid] + bc2[gid] + bc3[gid];
}

// ---------------- fold Q/K projections: Wqk = Wq*Wk^T, zb = bq*Wk^T ----------------
__global__ __launch_bounds__(256) void combine_qk(
    const float* __restrict__ Wq, const float* __restrict__ bq,
    const float* __restrict__ Wk,
    float* __restrict__ Wqk, float* __restrict__ zb)
{
  int gid = blockIdx.x*256 + threadIdx.x;
  if (gid < 4096) {
    int i = gid >> 6, j = gid & 63;
    float a = 0.f;
    for (int o=0;o<64;o++) a = fmaf(Wq[i*64+o], Wk[j*64+o], a);
    Wqk[i*64+j] = a;
  } else if (gid < 4160) {
    int j = gid - 4096;
    float a = 0.f;
    for (int o=0;o<64;o++) a = fmaf(bq[o], Wk[j*64+o], a);
    zb[j] = a;
  }
}

// ---------------- dilated conv block + residual, per (b,n) slice ----------------
__global__ __launch_bounds__(256,4) void conv_kernel(
    const float* __restrict__ x, const float* __restrict__ Wcomb,
    const float* __restrict__ bcomb, float* __restrict__ x1)
{
  __shared__ float xs[64*72];        // [f][t+4], t in [-4,68), zero-padded
  const int bn = blockIdx.x; const int b = bn >> 8; const int n = bn & 255;
  const int tid = threadIdx.x;
#pragma unroll
  for (int k=0;k<18;k++) xs[k*256+tid] = 0.f;
  __syncthreads();
  const float* xbase = x + ((size_t)b*TT)*SLICE + n*FDIM;
#pragma unroll
  for (int it=0; it<4; it++) {
    int flat4 = it*256 + tid;
    int t = flat4 >> 4, f4 = (flat4 & 15) << 2;
    float4 v = *(const float4*)(xbase + (size_t)t*SLICE + f4);
    xs[(f4+0)*72 + t+4] = v.x;
    xs[(f4+1)*72 + t+4] = v.y;
    xs[(f4+2)*72 + t+4] = v.z;
    xs[(f4+3)*72 + t+4] = v.w;
  }
  __syncthreads();
  const int o = tid & 63;            // lane -> output feature
  const int tb = (tid >> 6) << 4;    // wave -> 16-step t range (wave-uniform)
  float acc[16];
  const float bco = bcomb[o];
#pragma unroll
  for (int k=0;k<16;k++) acc[k] = bco;
  for (int i=0;i<FDIM;i++) {
    float xr[24];
#pragma unroll
    for (int q=0;q<6;q++) {
      float4 v = *(const float4*)&xs[i*72 + tb + q*4];
      xr[q*4+0]=v.x; xr[q*4+1]=v.y; xr[q*4+2]=v.z; xr[q*4+3]=v.w;
    }
#pragma unroll
    for (int j=0;j<7;j++) {
      float w = Wcomb[(j*FDIM+i)*FDIM + o];
#pragma unroll
      for (int k=0;k<16;k++) acc[k] = fmaf(xr[k+j+1], w, acc[k]);
    }
  }
  float* obase = x1 + ((size_t)b*TT)*SLICE + n*FDIM + o;
#pragma unroll
  for (int k=0;k<16;k++) {
    int t = tb + k;
    float c = acc[k];
    float outv = xs[o*72 + t+4] + (c > 0.f ? c : 0.f);
    obase[(size_t)t*SLICE] = outv;
  }
}

// ---------------- attention (diag softmax) + dense + inf-norm, per (b,t) ----------------
// 512 threads, 1 block/CU (LDS 140KB). Scores: wave w -> n-band nb=w&3 (64 n),
// m-half mh=w>>2 (128 m). Lane l=(li<<2)|lj, li<16, lj<4: 4n x 4m register tile,
// n(ii)=64nb+16ii+li, m(jj)=128mh+16st+4jj+lj, st<8. Per kc: 4 z-reads (16 distinct
// rows, 2-way bank alias = free) + 4 x-reads (4 rows x 16-lane bcast, free), 32 pkfma.
// Peak live regs ~90 < 128 (R6 lesson: hipcc caps at 128 here; 8x4 tile spilled).
// S/D reduced over lj (shfl_xor 1,2), halves exchanged via LDS. Projections stream
// operands from LDS (no 64-float register arrays).
__global__ __launch_bounds__(512,1) void attn_kernel(
    const float* __restrict__ x1,
    const float* __restrict__ Wqk, const float* __restrict__ zb,
    const float* __restrict__ Wv, const float* __restrict__ bv,
    const float* __restrict__ Wd, const float* __restrict__ bd,
    float* __restrict__ vout)
{
  __shared__ float lds[2*256*68 + 1024];
  float* xs  = lds;                  // [256][68] x rows
  float* zs  = lds + 256*68;         // [256][68] z rows -> o1 -> result
  float* exS = lds + 2*256*68;       // [2][256] denom halves; later nrm halves
  float* exD = exS + 512;            // [2][256] diag halves
  const int bt  = blockIdx.x;
  const int tid = threadIdx.x;
  const int w = tid >> 6, l = tid & 63;
  const int nb = w & 3, mh = w >> 2;
  const float* xsl = x1 + (size_t)bt*SLICE;

  // ---- stage-in x ----
  const float4* xb4 = (const float4*)xsl;
#pragma unroll
  for (int it=0; it<8; it++) {
    int flat4 = it*512 + tid;
    int row = flat4 >> 4, c = flat4 & 15;
    *(float4*)&xs[row*68 + c*4] = xb4[flat4];
  }
  __syncthreads();

  // ---- z-projection: thread (n = tid&255, h = tid>>8) computes z[n][32h..+32) ----
  const int n  = tid & 255;
  const int h  = tid >> 8;
  const int col0 = 32 * h;
  {
    v2f za[16];
#pragma unroll
    for (int j=0;j<16;j++) { v2f t; t.x = zb[col0+2*j]; t.y = zb[col0+2*j+1]; za[j] = t; }
    for (int q=0;q<16;q++) {
      float4 xc = *(const float4*)&xs[n*68 + 4*q];
      float xe[4] = {xc.x, xc.y, xc.z, xc.w};
#pragma unroll
      for (int e=0;e<4;e++) {
        int i = 4*q + e;
        v2f xv; xv.x = xe[e]; xv.y = xe[e];
        const float4* wr = (const float4*)(Wqk + i*64 + col0);
#pragma unroll
        for (int qq=0;qq<8;qq++) {
          float4 w4 = wr[qq];
          v2f wlo; wlo.x=w4.x; wlo.y=w4.y;
          v2f whi; whi.x=w4.z; whi.y=w4.w;
          za[2*qq]   = pkfma(xv, wlo, za[2*qq]);
          za[2*qq+1] = pkfma(xv, whi, za[2*qq+1]);
        }
      }
    }
#pragma unroll
    for (int qq=0;qq<8;qq++) {
      float4 t; t.x=za[2*qq].x; t.y=za[2*qq].y; t.z=za[2*qq+1].x; t.w=za[2*qq+1].y;
      *(float4*)&zs[n*68 + col0 + 4*qq] = t;
    }
  }
  __syncthreads();

  // ---- score phase: 4n x 4m register tiles ----
  float S[4] = {0,0,0,0};
  float D[4] = {0,0,0,0};
  {
    const int li = l >> 2, lj = l & 3;
    const float* zrow = &zs[(64*nb + li)*68];
    for (int st=0; st<8; st++) {
      const float* xrow = &xs[(128*mh + 16*st + lj)*68];
      v2f acc[4][4];
#pragma unroll
      for (int ii=0;ii<4;ii++)
#pragma unroll
        for (int jj=0;jj<4;jj++) { acc[ii][jj].x = 0.f; acc[ii][jj].y = 0.f; }
#pragma unroll
      for (int kc=0; kc<16; kc++) {
        float4 z4[4];
#pragma unroll
        for (int ii=0;ii<4;ii++) z4[ii] = *(const float4*)(zrow + ii*(16*68) + kc*4);
        float4 x4[4];
#pragma unroll
        for (int jj=0;jj<4;jj++) x4[jj] = *(const float4*)(xrow + jj*(4*68) + kc*4);
#pragma unroll
        for (int ii=0;ii<4;ii++) {
          v2f zlo; zlo.x=z4[ii].x; zlo.y=z4[ii].y;
          v2f zhi; zhi.x=z4[ii].z; zhi.y=z4[ii].w;
#pragma unroll
          for (int jj=0;jj<4;jj++) {
            v2f xlo; xlo.x=x4[jj].x; xlo.y=x4[jj].y;
            v2f xhi; xhi.x=x4[jj].z; xhi.y=x4[jj].w;
            acc[ii][jj] = pkfma(zlo, xlo, acc[ii][jj]);
            acc[ii][jj] = pkfma(zhi, xhi, acc[ii][jj]);
          }
        }
      }
#pragma unroll
      for (int ii=0;ii<4;ii++) {
#pragma unroll
        for (int jj=0;jj<4;jj++) {
          float s = (acc[ii][jj].x + acc[ii][jj].y) * 0.125f;
          int m  = 128*mh + 16*st + 4*jj + lj;
          int nn = 64*nb + 16*ii + li;
          if (m == nn) D[ii] = s;
          S[ii] += __expf(s);
        }
      }
    }
#pragma unroll
    for (int ii=0;ii<4;ii++) {
      S[ii] += __shfl_xor(S[ii], 1);
      S[ii] += __shfl_xor(S[ii], 2);
      D[ii] += __shfl_xor(D[ii], 1);
      D[ii] += __shfl_xor(D[ii], 2);
    }
    if (lj == 0) {
#pragma unroll
      for (int ii=0;ii<4;ii++) {
        int nn = 64*nb + 16*ii + li;
        exS[mh*256 + nn] = S[ii];
        exD[mh*256 + nn] = D[ii];
      }
    }
  }
  __syncthreads();

  // ---- epilogue: thread (n, h) ----
  const float Ssum = exS[n] + exS[256 + n];
  const float Dsum = exD[n] + exD[256 + n];
  const float ann = __expf(Dsum) / Ssum;

  // V-projection own col-half (stream x from LDS); o1 = x + relu(ann*(xWv+bv))
  {
    v2f va[16];
#pragma unroll
    for (int j=0;j<16;j++) { v2f t; t.x = bv[col0+2*j]; t.y = bv[col0+2*j+1]; va[j] = t; }
    for (int q=0;q<16;q++) {
      float4 xc = *(const float4*)&xs[n*68 + 4*q];
      float xe[4] = {xc.x, xc.y, xc.z, xc.w};
#pragma unroll
      for (int e=0;e<4;e++) {
        int i = 4*q + e;
        v2f xv; xv.x = xe[e]; xv.y = xe[e];
        const float4* wr = (const float4*)(Wv + i*64 + col0);
#pragma unroll
        for (int qq=0;qq<8;qq++) {
          float4 w4 = wr[qq];
          v2f wlo; wlo.x=w4.x; wlo.y=w4.y;
          v2f whi; whi.x=w4.z; whi.y=w4.w;
          va[2*qq]   = pkfma(xv, wlo, va[2*qq]);
          va[2*qq+1] = pkfma(xv, whi, va[2*qq+1]);
        }
      }
    }
#pragma unroll
    for (int qq=0;qq<8;qq++) {
      float4 xc = *(const float4*)&xs[n*68 + col0 + 4*qq];
      float g0 = ann * za_get(va, 4*qq+0);
      float g1 = ann * za_get(va, 4*qq+1);
      float g2 = ann * za_get(va, 4*qq+2);
      float g3 = ann * za_get(va, 4*qq+3);
      float4 t;
      t.x = xc.x + (g0 > 0.f ? g0 : 0.f);
      t.y = xc.y + (g1 > 0.f ? g1 : 0.f);
      t.z = xc.z + (g2 > 0.f ? g2 : 0.f);
      t.w = xc.w + (g3 > 0.f ? g3 : 0.f);
      *(float4*)&zs[n*68 + col0 + 4*qq] = t;   // z dead (score reads pre-barrier)
    }
  }
  __syncthreads();
  // dense projection own col-half (stream o1 from LDS)
  float dd[32];
  {
    v2f da[16];
#pragma unroll
    for (int j=0;j<16;j++) { v2f t; t.x = bd[col0+2*j]; t.y = bd[col0+2*j+1]; da[j] = t; }
    for (int q=0;q<16;q++) {
      float4 o4 = *(const float4*)&zs[n*68 + 4*q];
      float oe[4] = {o4.x, o4.y, o4.z, o4.w};
#pragma unroll
      for (int e=0;e<4;e++) {
        int i = 4*q + e;
        v2f xv; xv.x = oe[e]; xv.y = oe[e];
        const float4* wr = (const float4*)(Wd + i*64 + col0);
#pragma unroll
        for (int qq=0;qq<8;qq++) {
          float4 w4 = wr[qq];
          v2f wlo; wlo.x=w4.x; wlo.y=w4.y;
          v2f whi; whi.x=w4.z; whi.y=w4.w;
          da[2*qq]   = pkfma(xv, wlo, da[2*qq]);
          da[2*qq+1] = pkfma(xv, whi, da[2*qq+1]);
        }
      }
    }
#pragma unroll
    for (int o=0;o<32;o++) dd[o] = za_get(da, o);
  }
  float nh = 0.f;
#pragma unroll
  for (int o=0;o<32;o++) nh = fmaxf(nh, fabsf(dd[o]));
  exS[h*256 + n] = nh;   // safe: all Ssum reads happened before the previous barrier
  __syncthreads();
  const float nrm = fmaxf(exS[n], exS[256 + n]);
#pragma unroll
  for (int qq=0;qq<8;qq++) {
    float4 t;
    t.x = 0.5f*(dd[4*qq+0]/nrm + 1.f);
    t.y = 0.5f*(dd[4*qq+1]/nrm + 1.f);
    t.z = 0.5f*(dd[4*qq+2]/nrm + 1.f);
    t.w = 0.5f*(dd[4*qq+3]/nrm + 1.f);
    *(float4*)&zs[n*68 + col0 + 4*qq] = t;   // o1 reads all pre-barrier
  }
  __syncthreads();
  float4* ob4 = (float4*)(vout + (size_t)bt*SLICE);
#pragma unroll
  for (int it=0; it<8; it++) {
    int flat4 = it*512 + tid;
    int row = flat4 >> 4, c = flat4 & 15;
    ob4[flat4] = *(const float4*)&zs[row*68 + c*4];
  }
}

// ---------------- radix-select histograms (values are non-negative floats) ----------------
template<int LEVEL>
__global__ __launch_bounds__(256) void hist_kernel(
    const float* __restrict__ v, unsigned* __restrict__ ghist,
    const unsigned* __restrict__ pfx)
{
  __shared__ unsigned hh[4096];
  const int batch = blockIdx.x >> 5, chunk = blockIdx.x & 31;
  const int tid = threadIdx.x;
#pragma unroll
  for (int k=0;k<16;k++) hh[k*256+tid] = 0u;
  __syncthreads();
  const unsigned p = pfx ? pfx[batch] : 0u;
  const float4* vb = (const float4*)(v + (size_t)batch*(TT*SLICE)) + chunk*8192 + tid;
  for (int k=0;k<32;k++) {
    float4 q = vb[k*256];
    float e[4] = {q.x,q.y,q.z,q.w};
#pragma unroll
    for (int j=0;j<4;j++) {
      unsigned u = __float_as_uint(e[j]);
      if (LEVEL==1) atomicAdd(&hh[u>>20], 1u);
      else if ((u>>20)==p) atomicAdd(&hh[(u>>8)&0xFFFu], 1u);
    }
  }
  __syncthreads();
  unsigned* gh = ghist + batch*4096;
#pragma unroll
  for (int k=0;k<16;k++) { unsigned c = hh[k*256+tid]; if (c) atomicAdd(&gh[k*256+tid], c); }
}

__global__ __launch_bounds__(256) void hist8_kernel(
    const float* __restrict__ v, unsigned* __restrict__ ghist,
    const unsigned* __restrict__ pfx)
{
  __shared__ unsigned hh[256];
  const int batch = blockIdx.x >> 5, chunk = blockIdx.x & 31;
  const int tid = threadIdx.x;
  hh[tid] = 0u;
  __syncthreads();
  const unsigned p = pfx[batch];
  const float4* vb = (const float4*)(v + (size_t)batch*(TT*SLICE)) + chunk*8192 + tid;
  for (int k=0;k<32;k++) {
    float4 q = vb[k*256];
    float e[4] = {q.x,q.y,q.z,q.w};
#pragma unroll
    for (int j=0;j<4;j++) {
      unsigned u = __float_as_uint(e[j]);
      if ((u>>8)==p) atomicAdd(&hh[u & 255u], 1u);
    }
  }
  __syncthreads();
  unsigned c = hh[tid];
  if (c) atomicAdd(&ghist[batch*256+tid], c);
}

// ---------------- find bin containing the rank (block scan per batch) ----------------
template<int PER>
__global__ __launch_bounds__(256) void find_kernel(
    const unsigned* __restrict__ hist,
    const unsigned* __restrict__ rank_in, const unsigned* __restrict__ pfx_in,
    int pfx_shift, unsigned* __restrict__ pfx_out, unsigned* __restrict__ rank_out,
    float* __restrict__ mu, int final_level)
{
  __shared__ unsigned csum[256];
  const int batch = blockIdx.x;
  const int tid = threadIdx.x;
  const unsigned* hb = hist + batch*(PER*256);
  unsigned loc[PER];
  unsigned s = 0;
#pragma unroll
  for (int q=0;q<PER;q++) { loc[q] = hb[tid*PER+q]; s += loc[q]; }
  csum[tid] = s;
  __syncthreads();
  for (int off=1; off<256; off<<=1) {
    unsigned vv = csum[tid];
    unsigned ad = (tid >= off) ? csum[tid-off] : 0u;
    __syncthreads();
    csum[tid] = vv + ad;
    __syncthreads();
  }
  const unsigned rank = rank_in ? rank_in[batch] : RANK0;
  const unsigned excl = csum[tid] - s;
  if (rank >= excl && rank < excl + s) {
    unsigned r = rank - excl;
    int bin = 0;
#pragma unroll
    for (int q=0;q<PER;q++) {
      if (r < loc[q]) { bin = tid*PER + q; break; }
      r -= loc[q];
    }
    unsigned pf = pfx_in ? pfx_in[batch] : 0u;
    unsigned np = (pf << pfx_shift) | (unsigned)bin;
    if (final_level) { mu[batch] = __uint_as_float(np); }
    else { pfx_out[batch] = np; rank_out[batch] = r; }
  }
}

// ---------------- sigmoid + STE mask + predictor, per (b,t) ----------------
__global__ __launch_bounds__(256,2) void final_kernel(
    const float* __restrict__ v, const float* __restrict__ mu,
    const float* __restrict__ Wp, const float* __restrict__ bp,
    float* __restrict__ pred, float* __restrict__ mask)
{
  __shared__ float sl[NNODES*68];
  const int bt = blockIdx.x;
  const int b = bt >> 6;
  const int tid = threadIdx.x;
  const float4* vb4 = (const float4*)(v + (size_t)bt*SLICE);
#pragma unroll
  for (int it=0; it<16; it++) {
    int flat4 = it*256 + tid;
    int n = flat4 >> 4, f4 = (flat4 & 15) << 2;
    *(float4*)&sl[n*68 + f4] = vb4[flat4];
  }
  __syncthreads();
  const float muv = mu[b];
  float srow[64];
#pragma unroll
  for (int q=0;q<16;q++) {
    float4 vv = *(const float4*)&sl[tid*68 + q*4];
    float e0 = 1.f/(1.f + expf(-(vv.x - muv)));
    float e1 = 1.f/(1.f + expf(-(vv.y - muv)));
    float e2 = 1.f/(1.f + expf(-(vv.z - muv)));
    float e3 = 1.f/(1.f + expf(-(vv.w - muv)));
    float m0 = rintf(e0), m1 = rintf(e1), m2 = rintf(e2), m3 = rintf(e3);
    srow[q*4+0] = e0*m0; srow[q*4+1] = e1*m1; srow[q*4+2] = e2*m2; srow[q*4+3] = e3*m3;
    float4 w; w.x=m0; w.y=m1; w.z=m2; w.w=m3;
    *(float4*)&sl[tid*68 + q*4] = w;
  }
  __syncthreads();
  float4* mb4 = (float4*)(mask + (size_t)bt*SLICE);
#pragma unroll
  for (int it=0; it<16; it++) {
    int flat4 = it*256 + tid;
    int n = flat4 >> 4, f4 = (flat4 & 15) << 2;
    mb4[flat4] = *(const float4*)&sl[n*68 + f4];
  }
  float acc[64];
#pragma unroll
  for (int o=0;o<64;o++) acc[o]=0.f;
  for (int i=0;i<64;i++) {
    float sv = srow[i];
#pragma unroll
    for (int o=0;o<64;o++) acc[o] = fmaf(sv, Wp[i*64+o], acc[o]);
  }
  __syncthreads();
#pragma unroll
  for (int q=0;q<16;q++) {
    float4 w;
    w.x = acc[q*4+0]+bp[q*4+0]; w.y = acc[q*4+1]+bp[q*4+1];
    w.z = acc[q*4+2]+bp[q*4+2]; w.w = acc[q*4+3]+bp[q*4+3];
    *(float4*)&sl[tid*68 + q*4] = w;
  }
  __syncthreads();
  float4* pb4 = (float4*)(pred + (size_t)bt*SLICE);
#pragma unroll
  for (int it=0; it<16; it++) {
    int flat4 = it*256 + tid;
    int n = flat4 >> 4, f4 = (flat4 & 15) << 2;
    pb4[flat4] = *(const float4*)&sl[n*68 + f4];
  }
}

extern "C" void kernel_launch(void* const* d_in, const int* in_sizes, int n_in,
                              void* d_out, int out_size, void* d_ws, size_t ws_size,
                              hipStream_t stream) {
  const float* x   = (const float*)d_in[0];
  const float* Wc1 = (const float*)d_in[1];  const float* bc1 = (const float*)d_in[2];
  const float* Wc2 = (const float*)d_in[3];  const float* bc2 = (const float*)d_in[4];
  const float* Wc3 = (const float*)d_in[5];  const float* bc3 = (const float*)d_in[6];
  const float* Wq  = (const float*)d_in[7];  const float* bq  = (const float*)d_in[8];
  const float* Wk  = (const float*)d_in[9];
  const float* Wv  = (const float*)d_in[11]; const float* bv  = (const float*)d_in[12];
  const float* Wd  = (const float*)d_in[13]; const float* bd  = (const float*)d_in[14];
  const float* Wp  = (const float*)d_in[15]; const float* bp  = (const float*)d_in[16];

  float* pred = (float*)d_out;       // also holds pre-sigmoid v, overwritten in place
  float* mask = pred + NTOT;         // also holds conv output x1, overwritten in place

  unsigned* hist1 = (unsigned*)d_ws;           // 32*4096
  unsigned* hist2 = hist1 + 32*4096;           // 32*4096
  unsigned* hist3 = hist2 + 32*4096;           // 32*256
  unsigned* pfx1  = hist3 + 32*256;
  unsigned* rank1 = pfx1 + 32;
  unsigned* pfx2  = rank1 + 32;
  unsigned* rank2 = pfx2 + 32;
  float*    muv   = (float*)(rank2 + 32);
  float*    Wcomb = muv + 32;                  // 7*64*64
  float*    bcomb = Wcomb + 7*64*64;           // 64
  float*    Wqk   = bcomb + 64;                // 64*64
  float*    zbv   = Wqk + 64*64;               // 64

  hipMemsetAsync(d_ws, 0, (size_t)(32*4096*2 + 32*256)*sizeof(unsigned), stream);
  combine_w<<<112, 256, 0, stream>>>(Wc1,bc1,Wc2,bc2,Wc3,bc3,Wcomb,bcomb);
  combine_qk<<<17, 256, 0, stream>>>(Wq,bq,Wk,Wqk,zbv);
  conv_kernel<<<BB*NNODES, 256, 0, stream>>>(x, Wcomb, bcomb, mask /*x1*/);
  attn_kernel<<<BB*TT, 512, 0, stream>>>(mask /*x1*/, Wqk,zbv, Wv,bv,Wd,bd, pred /*v*/);
  hist_kernel<1><<<1024, 256, 0, stream>>>(pred, hist1, nullptr);
  find_kernel<16><<<32, 256, 0, stream>>>(hist1, nullptr, nullptr, 0, pfx1, rank1, nullptr, 0);
  hist_kernel<2><<<1024, 256, 0, stream>>>(pred, hist2, pfx1);
  find_kernel<16><<<32, 256, 0, stream>>>(hist2, rank1, pfx1, 12, pfx2, rank2, nullptr, 0);
  hist8_kernel<<<1024, 256, 0, stream>>>(pred, hist3, pfx2);
  find_kernel<1><<<32, 256, 0, stream>>>(hist3, rank2, pfx2, 8, nullptr, nullptr, muv, 1);
  final_kernel<<<BB*TT, 256, 0, stream>>>(pred /*v*/, muv, Wp, bp, pred, mask);
}

// Round 8
// 1760.986 us; speedup vs baseline: 4.8026x; 1.0860x over previous
//
#include <hip/hip_runtime.h>
#include <math.h>

#define BB 32
#define TT 64
#define NNODES 256
#define FDIM 64
#define SLICE (NNODES*FDIM)          // 16384 floats per (b,t) slice
#define NTOT (BB*TT*NNODES*FDIM)     // 33554432
#define RANK0 838860u                // ascending order-statistic index: T*N*F - k - 1, k=209715

typedef float v2f __attribute__((ext_vector_type(2)));
__device__ __forceinline__ v2f pkfma(v2f a, v2f b, v2f c) {
#if __has_builtin(__builtin_elementwise_fma)
  return __builtin_elementwise_fma(a, b, c);
#else
  v2f r; r.x = fmaf(a.x,b.x,c.x); r.y = fmaf(a.y,b.y,c.y); return r;
#endif
}
__device__ __forceinline__ float za_get(const v2f* a, int o) {
  return (o & 1) ? a[o>>1].y : a[o>>1].x;
}

// ---------------- weight combine: 7 effective taps (-3..+3) ----------------
__global__ __launch_bounds__(256) void combine_w(
    const float* __restrict__ Wc1, const float* __restrict__ bc1,
    const float* __restrict__ Wc2, const float* __restrict__ bc2,
    const float* __restrict__ Wc3, const float* __restrict__ bc3,
    float* __restrict__ Wcomb, float* __restrict__ bcomb)
{
  const int FF2 = FDIM*FDIM;
  int gid = blockIdx.x*256 + threadIdx.x;
  if (gid < 7*FF2) {
    int j = gid / FF2, r = gid % FF2;
    float v;
    switch (j) {
      case 0: v = Wc3[r]; break;                                   // offset -3
      case 1: v = Wc2[r]; break;                                   // offset -2
      case 2: v = Wc1[r]; break;                                   // offset -1
      case 3: v = Wc1[FF2+r] + Wc2[FF2+r] + Wc3[FF2+r]; break;     // offset  0
      case 4: v = Wc1[2*FF2+r]; break;                             // offset +1
      case 5: v = Wc2[2*FF2+r]; break;                             // offset +2
      default: v = Wc3[2*FF2+r]; break;                            // offset +3
    }
    Wcomb[gid] = v;
  }
  if (gid < FDIM) bcomb[gid] = bc1[gid] + bc2[gid] + bc3[gid];
}

// ---------------- fold Q/K projections: Wqk = Wq*Wk^T, zb = bq*Wk^T ----------------
__global__ __launch_bounds__(256) void combine_qk(
    const float* __restrict__ Wq, const float* __restrict__ bq,
    const float* __restrict__ Wk,
    float* __restrict__ Wqk, float* __restrict__ zb)
{
  int gid = blockIdx.x*256 + threadIdx.x;
  if (gid < 4096) {
    int i = gid >> 6, j = gid & 63;
    float a = 0.f;
    for (int o=0;o<64;o++) a = fmaf(Wq[i*64+o], Wk[j*64+o], a);
    Wqk[i*64+j] = a;
  } else if (gid < 4160) {
    int j = gid - 4096;
    float a = 0.f;
    for (int o=0;o<64;o++) a = fmaf(bq[o], Wk[j*64+o], a);
    zb[j] = a;
  }
}

// ---------------- dilated conv block + residual, per (b,n) slice ----------------
__global__ __launch_bounds__(256,4) void conv_kernel(
    const float* __restrict__ x, const float* __restrict__ Wcomb,
    const float* __restrict__ bcomb, float* __restrict__ x1)
{
  __shared__ float xs[64*72];        // [f][t+4], t in [-4,68), zero-padded
  const int bn = blockIdx.x; const int b = bn >> 8; const int n = bn & 255;
  const int tid = threadIdx.x;
#pragma unroll
  for (int k=0;k<18;k++) xs[k*256+tid] = 0.f;
  __syncthreads();
  const float* xbase = x + ((size_t)b*TT)*SLICE + n*FDIM;
#pragma unroll
  for (int it=0; it<4; it++) {
    int flat4 = it*256 + tid;
    int t = flat4 >> 4, f4 = (flat4 & 15) << 2;
    float4 v = *(const float4*)(xbase + (size_t)t*SLICE + f4);
    xs[(f4+0)*72 + t+4] = v.x;
    xs[(f4+1)*72 + t+4] = v.y;
    xs[(f4+2)*72 + t+4] = v.z;
    xs[(f4+3)*72 + t+4] = v.w;
  }
  __syncthreads();
  const int o = tid & 63;            // lane -> output feature
  const int tb = (tid >> 6) << 4;    // wave -> 16-step t range (wave-uniform)
  float acc[16];
  const float bco = bcomb[o];
#pragma unroll
  for (int k=0;k<16;k++) acc[k] = bco;
  for (int i=0;i<FDIM;i++) {
    float xr[24];
#pragma unroll
    for (int q=0;q<6;q++) {
      float4 v = *(const float4*)&xs[i*72 + tb + q*4];
      xr[q*4+0]=v.x; xr[q*4+1]=v.y; xr[q*4+2]=v.z; xr[q*4+3]=v.w;
    }
#pragma unroll
    for (int j=0;j<7;j++) {
      float w = Wcomb[(j*FDIM+i)*FDIM + o];
#pragma unroll
      for (int k=0;k<16;k++) acc[k] = fmaf(xr[k+j+1], w, acc[k]);
    }
  }
  float* obase = x1 + ((size_t)b*TT)*SLICE + n*FDIM + o;
#pragma unroll
  for (int k=0;k<16;k++) {
    int t = tb + k;
    float c = acc[k];
    float outv = xs[o*72 + t+4] + (c > 0.f ? c : 0.f);
    obase[(size_t)t*SLICE] = outv;
  }
}

// ---------------- attention part A: scores + softmax -> ann[bt][n] ----------------
// 512 threads, 1 block/CU. LDS: x[256][68] + z[256][68] + 2x512 exchange.
// Wave w = (nb = w&3, mh = w>>2): 64 n-rows x 128 m-cols. Lane l = (li<<2)|lj:
// 4n x 4m tile, n = 64nb+16ii+li, m = 128mh+16mt+4jj+lj. Per kc: 4 x-reads
// (4 rows x 16-bcast, conflict-free) + 4 z-reads (16 distinct rows, 2-way = free),
// 32 pkfma (ratio 4:1). kc body split in ii-halves to cap in-flight regs.
// No epilogue state in this kernel => peak live ~75 regs, no spill (R7 lesson).
__global__ __launch_bounds__(512,1) void attn_scores(
    const float* __restrict__ x1,
    const float* __restrict__ Wqk, const float* __restrict__ zb,
    float* __restrict__ anng)
{
  __shared__ float lds[2*256*68 + 1024];
  float* xs  = lds;                  // [256][68]
  float* zs  = lds + 256*68;         // [256][68]
  float* exS = lds + 2*256*68;       // [2][256] denom halves
  float* exD = exS + 512;            // [2][256] diag-dot halves
  const int bt  = blockIdx.x;
  const int tid = threadIdx.x;
  const int w = tid >> 6, l = tid & 63;
  const int nb = w & 3, mh = w >> 2;
  const float* xsl = x1 + (size_t)bt*SLICE;

  // stage-in x
  const float4* xb4 = (const float4*)xsl;
#pragma unroll
  for (int it=0; it<8; it++) {
    int flat4 = it*512 + tid;
    int row = flat4 >> 4, c = flat4 & 15;
    *(float4*)&xs[row*68 + c*4] = xb4[flat4];
  }
  __syncthreads();

  // z-projection: thread (n = tid&255, h = tid>>8) computes z[n][32h..+32)
  const int n = tid & 255, h = tid >> 8, col0 = 32*h;
  {
    v2f za[16];
#pragma unroll
    for (int j=0;j<16;j++) { v2f t; t.x = zb[col0+2*j]; t.y = zb[col0+2*j+1]; za[j] = t; }
    for (int q=0;q<16;q++) {
      float4 xc = *(const float4*)&xs[n*68 + 4*q];
      float xe[4] = {xc.x, xc.y, xc.z, xc.w};
#pragma unroll
      for (int e=0;e<4;e++) {
        int i = 4*q + e;
        v2f xv; xv.x = xe[e]; xv.y = xe[e];
        const float4* wr = (const float4*)(Wqk + i*64 + col0);
#pragma unroll
        for (int qq=0;qq<8;qq++) {
          float4 w4 = wr[qq];
          v2f wlo; wlo.x=w4.x; wlo.y=w4.y;
          v2f whi; whi.x=w4.z; whi.y=w4.w;
          za[2*qq]   = pkfma(xv, wlo, za[2*qq]);
          za[2*qq+1] = pkfma(xv, whi, za[2*qq+1]);
        }
      }
    }
#pragma unroll
    for (int qq=0;qq<8;qq++) {
      float4 t; t.x=za[2*qq].x; t.y=za[2*qq].y; t.z=za[2*qq+1].x; t.w=za[2*qq+1].y;
      *(float4*)&zs[n*68 + col0 + 4*qq] = t;
    }
  }
  __syncthreads();

  // score sweep, exp-sum only (diag handled after)
  float S[4] = {0,0,0,0};
  {
    const int li = l >> 2, lj = l & 3;
    const float* zrow = &zs[(64*nb + li)*68];
    for (int mt=0; mt<8; mt++) {
      const float* xrow = &xs[(128*mh + 16*mt + lj)*68];
      v2f acc[4][4];
#pragma unroll
      for (int ii=0;ii<4;ii++)
#pragma unroll
        for (int jj=0;jj<4;jj++) { acc[ii][jj].x = 0.f; acc[ii][jj].y = 0.f; }
#pragma unroll
      for (int kc=0; kc<16; kc++) {
        float4 x4[4];
#pragma unroll
        for (int jj=0;jj<4;jj++) x4[jj] = *(const float4*)(xrow + jj*(4*68) + kc*4);
        // ii-half 0/1: limit in-flight z regs
#pragma unroll
        for (int ih=0; ih<2; ih++) {
          float4 z4a = *(const float4*)(zrow + (2*ih+0)*(16*68) + kc*4);
          float4 z4b = *(const float4*)(zrow + (2*ih+1)*(16*68) + kc*4);
          v2f zalo; zalo.x=z4a.x; zalo.y=z4a.y;
          v2f zahi; zahi.x=z4a.z; zahi.y=z4a.w;
          v2f zblo; zblo.x=z4b.x; zblo.y=z4b.y;
          v2f zbhi; zbhi.x=z4b.z; zbhi.y=z4b.w;
#pragma unroll
          for (int jj=0;jj<4;jj++) {
            v2f xlo; xlo.x=x4[jj].x; xlo.y=x4[jj].y;
            v2f xhi; xhi.x=x4[jj].z; xhi.y=x4[jj].w;
            acc[2*ih+0][jj] = pkfma(zalo, xlo, acc[2*ih+0][jj]);
            acc[2*ih+0][jj] = pkfma(zahi, xhi, acc[2*ih+0][jj]);
            acc[2*ih+1][jj] = pkfma(zblo, xlo, acc[2*ih+1][jj]);
            acc[2*ih+1][jj] = pkfma(zbhi, xhi, acc[2*ih+1][jj]);
          }
        }
      }
#pragma unroll
      for (int ii=0;ii<4;ii++) {
#pragma unroll
        for (int jj=0;jj<4;jj++) {
          float s = (acc[ii][jj].x + acc[ii][jj].y) * 0.125f;
          S[ii] += __expf(s);
        }
      }
    }
#pragma unroll
    for (int ii=0;ii<4;ii++) {
      S[ii] += __shfl_xor(S[ii], 1);
      S[ii] += __shfl_xor(S[ii], 2);
    }
    if (lj == 0) {
#pragma unroll
      for (int ii=0;ii<4;ii++) exS[mh*256 + 64*nb + 16*ii + li] = S[ii];
    }
  }
  // diag half-dot: z[n][col0..]*x[n][col0..]
  float dh = 0.f;
#pragma unroll
  for (int q=0;q<8;q++) {
    float4 zv = *(const float4*)&zs[n*68 + col0 + 4*q];
    float4 xv = *(const float4*)&xs[n*68 + col0 + 4*q];
    dh = fmaf(zv.x, xv.x, dh);
    dh = fmaf(zv.y, xv.y, dh);
    dh = fmaf(zv.z, xv.z, dh);
    dh = fmaf(zv.w, xv.w, dh);
  }
  exD[h*256 + n] = dh;
  __syncthreads();
  if (h == 0) {
    float Ssum = exS[n] + exS[256 + n];
    float diag = (exD[n] + exD[256 + n]) * 0.125f;
    anng[(size_t)bt*256 + n] = __expf(diag) / Ssum;
  }
}

// ---------------- attention part B: o1 = x + relu(ann*(xWv+bv)); v = dense+norm ----------------
// 512 threads, 2 blocks/CU (LDS 71680 B). Thread (n = tid&255, h = tid>>8) owns
// row n, column-half [32h,32h+32). o1 half kept in 32 regs, exchanged via xs rows;
// nrm via 512-float LDS exchange. Peak live ~85 regs.
__global__ __launch_bounds__(512,1) void attn_apply(
    const float* __restrict__ x1, const float* __restrict__ anng,
    const float* __restrict__ Wv, const float* __restrict__ bv,
    const float* __restrict__ Wd, const float* __restrict__ bd,
    float* __restrict__ vout)
{
  __shared__ float xs[256*68];
  __shared__ float exN[512];
  const int bt  = blockIdx.x;
  const int tid = threadIdx.x;
  const int n = tid & 255, h = tid >> 8, col0 = 32*h;
  const float* xsl = x1 + (size_t)bt*SLICE;

  const float4* xb4 = (const float4*)xsl;
#pragma unroll
  for (int it=0; it<8; it++) {
    int flat4 = it*512 + tid;
    int row = flat4 >> 4, c = flat4 & 15;
    *(float4*)&xs[row*68 + c*4] = xb4[flat4];
  }
  __syncthreads();

  const float ann = anng[(size_t)bt*256 + n];

  // V-projection own col-half, stream x row from LDS; o1own in regs
  float o1own[32];
  {
    v2f va[16];
#pragma unroll
    for (int j=0;j<16;j++) { v2f t; t.x = bv[col0+2*j]; t.y = bv[col0+2*j+1]; va[j] = t; }
    for (int q=0;q<16;q++) {
      float4 xc = *(const float4*)&xs[n*68 + 4*q];
      float xe[4] = {xc.x, xc.y, xc.z, xc.w};
#pragma unroll
      for (int e=0;e<4;e++) {
        int i = 4*q + e;
        v2f xv; xv.x = xe[e]; xv.y = xe[e];
        const float4* wr = (const float4*)(Wv + i*64 + col0);
#pragma unroll
        for (int qq=0;qq<8;qq++) {
          float4 w4 = wr[qq];
          v2f wlo; wlo.x=w4.x; wlo.y=w4.y;
          v2f whi; whi.x=w4.z; whi.y=w4.w;
          va[2*qq]   = pkfma(xv, wlo, va[2*qq]);
          va[2*qq+1] = pkfma(xv, whi, va[2*qq+1]);
        }
      }
    }
#pragma unroll
    for (int qq=0;qq<8;qq++) {
      float4 xc = *(const float4*)&xs[n*68 + col0 + 4*qq];
      float g0 = ann * za_get(va, 4*qq+0);
      float g1 = ann * za_get(va, 4*qq+1);
      float g2 = ann * za_get(va, 4*qq+2);
      float g3 = ann * za_get(va, 4*qq+3);
      o1own[4*qq+0] = xc.x + (g0 > 0.f ? g0 : 0.f);
      o1own[4*qq+1] = xc.y + (g1 > 0.f ? g1 : 0.f);
      o1own[4*qq+2] = xc.z + (g2 > 0.f ? g2 : 0.f);
      o1own[4*qq+3] = xc.w + (g3 > 0.f ? g3 : 0.f);
    }
  }
  __syncthreads();                   // all V-proj x reads complete
#pragma unroll
  for (int qq=0;qq<8;qq++) {
    float4 t; t.x=o1own[4*qq+0]; t.y=o1own[4*qq+1]; t.z=o1own[4*qq+2]; t.w=o1own[4*qq+3];
    *(float4*)&xs[n*68 + col0 + 4*qq] = t;   // xs now holds o1
  }
  __syncthreads();

  // dense projection own col-half, stream o1 row from LDS
  float dd[32];
  {
    v2f da[16];
#pragma unroll
    for (int j=0;j<16;j++) { v2f t; t.x = bd[col0+2*j]; t.y = bd[col0+2*j+1]; da[j] = t; }
    for (int q=0;q<16;q++) {
      float4 o4 = *(const float4*)&xs[n*68 + 4*q];
      float oe[4] = {o4.x, o4.y, o4.z, o4.w};
#pragma unroll
      for (int e=0;e<4;e++) {
        int i = 4*q + e;
        v2f xv; xv.x = oe[e]; xv.y = oe[e];
        const float4* wr = (const float4*)(Wd + i*64 + col0);
#pragma unroll
        for (int qq=0;qq<8;qq++) {
          float4 w4 = wr[qq];
          v2f wlo; wlo.x=w4.x; wlo.y=w4.y;
          v2f whi; whi.x=w4.z; whi.y=w4.w;
          da[2*qq]   = pkfma(xv, wlo, da[2*qq]);
          da[2*qq+1] = pkfma(xv, whi, da[2*qq+1]);
        }
      }
    }
#pragma unroll
    for (int o=0;o<32;o++) dd[o] = za_get(da, o);
  }
  float nh = 0.f;
#pragma unroll
  for (int o=0;o<32;o++) nh = fmaxf(nh, fabsf(dd[o]));
  exN[h*256 + n] = nh;
  __syncthreads();                   // also fences all dense o1-reads of xs
  const float nrm = fmaxf(exN[n], exN[256 + n]);
#pragma unroll
  for (int qq=0;qq<8;qq++) {
    float4 t;
    t.x = 0.5f*(dd[4*qq+0]/nrm + 1.f);
    t.y = 0.5f*(dd[4*qq+1]/nrm + 1.f);
    t.z = 0.5f*(dd[4*qq+2]/nrm + 1.f);
    t.w = 0.5f*(dd[4*qq+3]/nrm + 1.f);
    *(float4*)&xs[n*68 + col0 + 4*qq] = t;   // xs now holds v
  }
  __syncthreads();
  float4* ob4 = (float4*)(vout + (size_t)bt*SLICE);
#pragma unroll
  for (int it=0; it<8; it++) {
    int flat4 = it*512 + tid;
    int row = flat4 >> 4, c = flat4 & 15;
    ob4[flat4] = *(const float4*)&xs[row*68 + c*4];
  }
}

// ---------------- radix-select histograms (values are non-negative floats) ----------------
template<int LEVEL>
__global__ __launch_bounds__(256) void hist_kernel(
    const float* __restrict__ v, unsigned* __restrict__ ghist,
    const unsigned* __restrict__ pfx)
{
  __shared__ unsigned hh[4096];
  const int batch = blockIdx.x >> 5, chunk = blockIdx.x & 31;
  const int tid = threadIdx.x;
#pragma unroll
  for (int k=0;k<16;k++) hh[k*256+tid] = 0u;
  __syncthreads();
  const unsigned p = pfx ? pfx[batch] : 0u;
  const float4* vb = (const float4*)(v + (size_t)batch*(TT*SLICE)) + chunk*8192 + tid;
  for (int k=0;k<32;k++) {
    float4 q = vb[k*256];
    float e[4] = {q.x,q.y,q.z,q.w};
#pragma unroll
    for (int j=0;j<4;j++) {
      unsigned u = __float_as_uint(e[j]);
      if (LEVEL==1) atomicAdd(&hh[u>>20], 1u);
      else if ((u>>20)==p) atomicAdd(&hh[(u>>8)&0xFFFu], 1u);
    }
  }
  __syncthreads();
  unsigned* gh = ghist + batch*4096;
#pragma unroll
  for (int k=0;k<16;k++) { unsigned c = hh[k*256+tid]; if (c) atomicAdd(&gh[k*256+tid], c); }
}

__global__ __launch_bounds__(256) void hist8_kernel(
    const float* __restrict__ v, unsigned* __restrict__ ghist,
    const unsigned* __restrict__ pfx)
{
  __shared__ unsigned hh[256];
  const int batch = blockIdx.x >> 5, chunk = blockIdx.x & 31;
  const int tid = threadIdx.x;
  hh[tid] = 0u;
  __syncthreads();
  const unsigned p = pfx[batch];
  const float4* vb = (const float4*)(v + (size_t)batch*(TT*SLICE)) + chunk*8192 + tid;
  for (int k=0;k<32;k++) {
    float4 q = vb[k*256];
    float e[4] = {q.x,q.y,q.z,q.w};
#pragma unroll
    for (int j=0;j<4;j++) {
      unsigned u = __float_as_uint(e[j]);
      if ((u>>8)==p) atomicAdd(&hh[u & 255u], 1u);
    }
  }
  __syncthreads();
  unsigned c = hh[tid];
  if (c) atomicAdd(&ghist[batch*256+tid], c);
}

// ---------------- find bin containing the rank (block scan per batch) ----------------
template<int PER>
__global__ __launch_bounds__(256) void find_kernel(
    const unsigned* __restrict__ hist,
    const unsigned* __restrict__ rank_in, const unsigned* __restrict__ pfx_in,
    int pfx_shift, unsigned* __restrict__ pfx_out, unsigned* __restrict__ rank_out,
    float* __restrict__ mu, int final_level)
{
  __shared__ unsigned csum[256];
  const int batch = blockIdx.x;
  const int tid = threadIdx.x;
  const unsigned* hb = hist + batch*(PER*256);
  unsigned loc[PER];
  unsigned s = 0;
#pragma unroll
  for (int q=0;q<PER;q++) { loc[q] = hb[tid*PER+q]; s += loc[q]; }
  csum[tid] = s;
  __syncthreads();
  for (int off=1; off<256; off<<=1) {
    unsigned vv = csum[tid];
    unsigned ad = (tid >= off) ? csum[tid-off] : 0u;
    __syncthreads();
    csum[tid] = vv + ad;
    __syncthreads();
  }
  const unsigned rank = rank_in ? rank_in[batch] : RANK0;
  const unsigned excl = csum[tid] - s;
  if (rank >= excl && rank < excl + s) {
    unsigned r = rank - excl;
    int bin = 0;
#pragma unroll
    for (int q=0;q<PER;q++) {
      if (r < loc[q]) { bin = tid*PER + q; break; }
      r -= loc[q];
    }
    unsigned pf = pfx_in ? pfx_in[batch] : 0u;
    unsigned np = (pf << pfx_shift) | (unsigned)bin;
    if (final_level) { mu[batch] = __uint_as_float(np); }
    else { pfx_out[batch] = np; rank_out[batch] = r; }
  }
}

// ---------------- sigmoid + STE mask + predictor, per (b,t) ----------------
__global__ __launch_bounds__(256,2) void final_kernel(
    const float* __restrict__ v, const float* __restrict__ mu,
    const float* __restrict__ Wp, const float* __restrict__ bp,
    float* __restrict__ pred, float* __restrict__ mask)
{
  __shared__ float sl[NNODES*68];
  const int bt = blockIdx.x;
  const int b = bt >> 6;
  const int tid = threadIdx.x;
  const float4* vb4 = (const float4*)(v + (size_t)bt*SLICE);
#pragma unroll
  for (int it=0; it<16; it++) {
    int flat4 = it*256 + tid;
    int n = flat4 >> 4, f4 = (flat4 & 15) << 2;
    *(float4*)&sl[n*68 + f4] = vb4[flat4];
  }
  __syncthreads();
  const float muv = mu[b];
  float srow[64];
#pragma unroll
  for (int q=0;q<16;q++) {
    float4 vv = *(const float4*)&sl[tid*68 + q*4];
    float e0 = 1.f/(1.f + expf(-(vv.x - muv)));
    float e1 = 1.f/(1.f + expf(-(vv.y - muv)));
    float e2 = 1.f/(1.f + expf(-(vv.z - muv)));
    float e3 = 1.f/(1.f + expf(-(vv.w - muv)));
    float m0 = rintf(e0), m1 = rintf(e1), m2 = rintf(e2), m3 = rintf(e3);
    srow[q*4+0] = e0*m0; srow[q*4+1] = e1*m1; srow[q*4+2] = e2*m2; srow[q*4+3] = e3*m3;
    float4 w; w.x=m0; w.y=m1; w.z=m2; w.w=m3;
    *(float4*)&sl[tid*68 + q*4] = w;
  }
  __syncthreads();
  float4* mb4 = (float4*)(mask + (size_t)bt*SLICE);
#pragma unroll
  for (int it=0; it<16; it++) {
    int flat4 = it*256 + tid;
    int n = flat4 >> 4, f4 = (flat4 & 15) << 2;
    mb4[flat4] = *(const float4*)&sl[n*68 + f4];
  }
  float acc[64];
#pragma unroll
  for (int o=0;o<64;o++) acc[o]=0.f;
  for (int i=0;i<64;i++) {
    float sv = srow[i];
#pragma unroll
    for (int o=0;o<64;o++) acc[o] = fmaf(sv, Wp[i*64+o], acc[o]);
  }
  __syncthreads();
#pragma unroll
  for (int q=0;q<16;q++) {
    float4 w;
    w.x = acc[q*4+0]+bp[q*4+0]; w.y = acc[q*4+1]+bp[q*4+1];
    w.z = acc[q*4+2]+bp[q*4+2]; w.w = acc[q*4+3]+bp[q*4+3];
    *(float4*)&sl[tid*68 + q*4] = w;
  }
  __syncthreads();
  float4* pb4 = (float4*)(pred + (size_t)bt*SLICE);
#pragma unroll
  for (int it=0; it<16; it++) {
    int flat4 = it*256 + tid;
    int n = flat4 >> 4, f4 = (flat4 & 15) << 2;
    pb4[flat4] = *(const float4*)&sl[n*68 + f4];
  }
}

extern "C" void kernel_launch(void* const* d_in, const int* in_sizes, int n_in,
                              void* d_out, int out_size, void* d_ws, size_t ws_size,
                              hipStream_t stream) {
  const float* x   = (const float*)d_in[0];
  const float* Wc1 = (const float*)d_in[1];  const float* bc1 = (const float*)d_in[2];
  const float* Wc2 = (const float*)d_in[3];  const float* bc2 = (const float*)d_in[4];
  const float* Wc3 = (const float*)d_in[5];  const float* bc3 = (const float*)d_in[6];
  const float* Wq  = (const float*)d_in[7];  const float* bq  = (const float*)d_in[8];
  const float* Wk  = (const float*)d_in[9];
  const float* Wv  = (const float*)d_in[11]; const float* bv  = (const float*)d_in[12];
  const float* Wd  = (const float*)d_in[13]; const float* bd  = (const float*)d_in[14];
  const float* Wp  = (const float*)d_in[15]; const float* bp  = (const float*)d_in[16];

  float* pred = (float*)d_out;       // also holds pre-sigmoid v, overwritten in place
  float* mask = pred + NTOT;         // also holds conv output x1, overwritten in place

  unsigned* hist1 = (unsigned*)d_ws;           // 32*4096
  unsigned* hist2 = hist1 + 32*4096;           // 32*4096
  unsigned* hist3 = hist2 + 32*4096;           // 32*256
  unsigned* pfx1  = hist3 + 32*256;
  unsigned* rank1 = pfx1 + 32;
  unsigned* pfx2  = rank1 + 32;
  unsigned* rank2 = pfx2 + 32;
  float*    muv   = (float*)(rank2 + 32);
  float*    Wcomb = muv + 32;                  // 7*64*64
  float*    bcomb = Wcomb + 7*64*64;           // 64
  float*    Wqk   = bcomb + 64;                // 64*64
  float*    zbv   = Wqk + 64*64;               // 64
  float*    anng  = zbv + 64;                  // BB*TT*256 = 524288 floats (2 MB)

  hipMemsetAsync(d_ws, 0, (size_t)(32*4096*2 + 32*256)*sizeof(unsigned), stream);
  combine_w<<<112, 256, 0, stream>>>(Wc1,bc1,Wc2,bc2,Wc3,bc3,Wcomb,bcomb);
  combine_qk<<<17, 256, 0, stream>>>(Wq,bq,Wk,Wqk,zbv);
  conv_kernel<<<BB*NNODES, 256, 0, stream>>>(x, Wcomb, bcomb, mask /*x1*/);
  attn_scores<<<BB*TT, 512, 0, stream>>>(mask /*x1*/, Wqk, zbv, anng);
  attn_apply<<<BB*TT, 512, 0, stream>>>(mask /*x1*/, anng, Wv,bv,Wd,bd, pred /*v*/);
  hist_kernel<1><<<1024, 256, 0, stream>>>(pred, hist1, nullptr);
  find_kernel<16><<<32, 256, 0, stream>>>(hist1, nullptr, nullptr, 0, pfx1, rank1, nullptr, 0);
  hist_kernel<2><<<1024, 256, 0, stream>>>(pred, hist2, pfx1);
  find_kernel<16><<<32, 256, 0, stream>>>(hist2, rank1, pfx1, 12, pfx2, rank2, nullptr, 0);
  hist8_kernel<<<1024, 256, 0, stream>>>(pred, hist3, pfx2);
  find_kernel<1><<<32, 256, 0, stream>>>(hist3, rank2, pfx2, 8, nullptr, nullptr, muv, 1);
  final_kernel<<<BB*TT, 256, 0, stream>>>(pred /*v*/, muv, Wp, bp, pred, mask);
}

// Round 9
// 1707.206 us; speedup vs baseline: 4.9538x; 1.0315x over previous
//
#include <hip/hip_runtime.h>
#include <math.h>

#define BB 32
#define TT 64
#define NNODES 256
#define FDIM 64
#define SLICE (NNODES*FDIM)          // 16384 floats per (b,t) slice
#define NTOT (BB*TT*NNODES*FDIM)     // 33554432
#define RANK0 838860u                // ascending order-statistic index: T*N*F - k - 1, k=209715

typedef float v2f __attribute__((ext_vector_type(2)));
__device__ __forceinline__ v2f pkfma(v2f a, v2f b, v2f c) {
#if __has_builtin(__builtin_elementwise_fma)
  return __builtin_elementwise_fma(a, b, c);
#else
  v2f r; r.x = fmaf(a.x,b.x,c.x); r.y = fmaf(a.y,b.y,c.y); return r;
#endif
}
__device__ __forceinline__ float za_get(const v2f* a, int o) {
  return (o & 1) ? a[o>>1].y : a[o>>1].x;
}

// ---------------- weight combine: 7 effective taps (-3..+3) ----------------
__global__ __launch_bounds__(256) void combine_w(
    const float* __restrict__ Wc1, const float* __restrict__ bc1,
    const float* __restrict__ Wc2, const float* __restrict__ bc2,
    const float* __restrict__ Wc3, const float* __restrict__ bc3,
    float* __restrict__ Wcomb, float* __restrict__ bcomb)
{
  const int FF2 = FDIM*FDIM;
  int gid = blockIdx.x*256 + threadIdx.x;
  if (gid < 7*FF2) {
    int j = gid / FF2, r = gid % FF2;
    float v;
    switch (j) {
      case 0: v = Wc3[r]; break;                                   // offset -3
      case 1: v = Wc2[r]; break;                                   // offset -2
      case 2: v = Wc1[r]; break;                                   // offset -1
      case 3: v = Wc1[FF2+r] + Wc2[FF2+r] + Wc3[FF2+r]; break;     // offset  0
      case 4: v = Wc1[2*FF2+r]; break;                             // offset +1
      case 5: v = Wc2[2*FF2+r]; break;                             // offset +2
      default: v = Wc3[2*FF2+r]; break;                            // offset +3
    }
    Wcomb[gid] = v;
  }
  if (gid < FDIM) bcomb[gid] = bc1[gid] + bc2[gid] + bc3[gid];
}

// ---------------- fold Q/K projections: Wqk = Wq*Wk^T, zb = bq*Wk^T ----------------
__global__ __launch_bounds__(256) void combine_qk(
    const float* __restrict__ Wq, const float* __restrict__ bq,
    const float* __restrict__ Wk,
    float* __restrict__ Wqk, float* __restrict__ zb)
{
  int gid = blockIdx.x*256 + threadIdx.x;
  if (gid < 4096) {
    int i = gid >> 6, j = gid & 63;
    float a = 0.f;
    for (int o=0;o<64;o++) a = fmaf(Wq[i*64+o], Wk[j*64+o], a);
    Wqk[i*64+j] = a;
  } else if (gid < 4160) {
    int j = gid - 4096;
    float a = 0.f;
    for (int o=0;o<64;o++) a = fmaf(bq[o], Wk[j*64+o], a);
    zb[j] = a;
  }
}

// ---------------- dilated conv block + residual, per (b,n) slice ----------------
__global__ __launch_bounds__(256,4) void conv_kernel(
    const float* __restrict__ x, const float* __restrict__ Wcomb,
    const float* __restrict__ bcomb, float* __restrict__ x1)
{
  __shared__ float xs[64*72];        // [f][t+4], t in [-4,68), zero-padded
  const int bn = blockIdx.x; const int b = bn >> 8; const int n = bn & 255;
  const int tid = threadIdx.x;
#pragma unroll
  for (int k=0;k<18;k++) xs[k*256+tid] = 0.f;
  __syncthreads();
  const float* xbase = x + ((size_t)b*TT)*SLICE + n*FDIM;
#pragma unroll
  for (int it=0; it<4; it++) {
    int flat4 = it*256 + tid;
    int t = flat4 >> 4, f4 = (flat4 & 15) << 2;
    float4 v = *(const float4*)(xbase + (size_t)t*SLICE + f4);
    xs[(f4+0)*72 + t+4] = v.x;
    xs[(f4+1)*72 + t+4] = v.y;
    xs[(f4+2)*72 + t+4] = v.z;
    xs[(f4+3)*72 + t+4] = v.w;
  }
  __syncthreads();
  const int o = tid & 63;            // lane -> output feature
  const int tb = (tid >> 6) << 4;    // wave -> 16-step t range (wave-uniform)
  float acc[16];
  const float bco = bcomb[o];
#pragma unroll
  for (int k=0;k<16;k++) acc[k] = bco;
  for (int i=0;i<FDIM;i++) {
    float xr[24];
#pragma unroll
    for (int q=0;q<6;q++) {
      float4 v = *(const float4*)&xs[i*72 + tb + q*4];
      xr[q*4+0]=v.x; xr[q*4+1]=v.y; xr[q*4+2]=v.z; xr[q*4+3]=v.w;
    }
#pragma unroll
    for (int j=0;j<7;j++) {
      float w = Wcomb[(j*FDIM+i)*FDIM + o];
#pragma unroll
      for (int k=0;k<16;k++) acc[k] = fmaf(xr[k+j+1], w, acc[k]);
    }
  }
  float* obase = x1 + ((size_t)b*TT)*SLICE + n*FDIM + o;
#pragma unroll
  for (int k=0;k<16;k++) {
    int t = tb + k;
    float c = acc[k];
    float outv = xs[o*72 + t+4] + (c > 0.f ? c : 0.f);
    obase[(size_t)t*SLICE] = outv;
  }
}

// ---------------- attention part A: scores + softmax -> ann[bt][n] ----------------
// R9: all local arrays indexed with compile-time constants only (rule #20 — the
// former xe[e]/xr[i] runtime-indexed loops were scratch-allocated and caused the
// ~380 MB/dispatch of phantom HBM traffic seen in R2..R8).
__global__ __launch_bounds__(512,1) void attn_scores(
    const float* __restrict__ x1,
    const float* __restrict__ Wqk, const float* __restrict__ zb,
    float* __restrict__ anng)
{
  __shared__ float lds[2*256*68 + 1024];
  float* xs  = lds;                  // [256][68]
  float* zs  = lds + 256*68;         // [256][68]
  float* exS = lds + 2*256*68;       // [2][256] denom halves
  float* exD = exS + 512;            // [2][256] diag-dot halves
  const int bt  = blockIdx.x;
  const int tid = threadIdx.x;
  const int w = tid >> 6, l = tid & 63;
  const int nb = w & 3, mh = w >> 2;
  const float* xsl = x1 + (size_t)bt*SLICE;

  // stage-in x
  const float4* xb4 = (const float4*)xsl;
#pragma unroll
  for (int it=0; it<8; it++) {
    int flat4 = it*512 + tid;
    int row = flat4 >> 4, c = flat4 & 15;
    *(float4*)&xs[row*68 + c*4] = xb4[flat4];
  }
  __syncthreads();

  // z-projection: thread (n = tid&255, h = tid>>8) computes z[n][32h..+32)
  const int n = tid & 255, h = tid >> 8, col0 = 32*h;
  {
    v2f za[16];
#pragma unroll
    for (int j=0;j<16;j++) { v2f t; t.x = zb[col0+2*j]; t.y = zb[col0+2*j+1]; za[j] = t; }
    auto zstep = [&](float v_, const float* wrow) {
      v2f xv; xv.x = v_; xv.y = v_;
      const float4* wr = (const float4*)wrow;
#pragma unroll
      for (int qq=0; qq<8; qq++) {
        float4 w4 = wr[qq];
        v2f wlo; wlo.x=w4.x; wlo.y=w4.y;
        v2f whi; whi.x=w4.z; whi.y=w4.w;
        za[2*qq]   = pkfma(xv, wlo, za[2*qq]);
        za[2*qq+1] = pkfma(xv, whi, za[2*qq+1]);
      }
    };
    for (int q=0;q<16;q++) {
      float4 xc = *(const float4*)&xs[n*68 + 4*q];
      const float* wb = Wqk + (4*q)*64 + col0;
      zstep(xc.x, wb);
      zstep(xc.y, wb + 64);
      zstep(xc.z, wb + 128);
      zstep(xc.w, wb + 192);
    }
#pragma unroll
    for (int qq=0;qq<8;qq++) {
      float4 t; t.x=za[2*qq].x; t.y=za[2*qq].y; t.z=za[2*qq+1].x; t.w=za[2*qq+1].y;
      *(float4*)&zs[n*68 + col0 + 4*qq] = t;
    }
  }
  __syncthreads();

  // score sweep, exp-sum only (diag handled after)
  float S[4] = {0,0,0,0};
  {
    const int li = l >> 2, lj = l & 3;
    const float* zrow = &zs[(64*nb + li)*68];
    for (int mt=0; mt<8; mt++) {
      const float* xrow = &xs[(128*mh + 16*mt + lj)*68];
      v2f acc[4][4];
#pragma unroll
      for (int ii=0;ii<4;ii++)
#pragma unroll
        for (int jj=0;jj<4;jj++) { acc[ii][jj].x = 0.f; acc[ii][jj].y = 0.f; }
#pragma unroll
      for (int kc=0; kc<16; kc++) {
        float4 x4[4];
#pragma unroll
        for (int jj=0;jj<4;jj++) x4[jj] = *(const float4*)(xrow + jj*(4*68) + kc*4);
#pragma unroll
        for (int ih=0; ih<2; ih++) {
          float4 z4a = *(const float4*)(zrow + (2*ih+0)*(16*68) + kc*4);
          float4 z4b = *(const float4*)(zrow + (2*ih+1)*(16*68) + kc*4);
          v2f zalo; zalo.x=z4a.x; zalo.y=z4a.y;
          v2f zahi; zahi.x=z4a.z; zahi.y=z4a.w;
          v2f zblo; zblo.x=z4b.x; zblo.y=z4b.y;
          v2f zbhi; zbhi.x=z4b.z; zbhi.y=z4b.w;
#pragma unroll
          for (int jj=0;jj<4;jj++) {
            v2f xlo; xlo.x=x4[jj].x; xlo.y=x4[jj].y;
            v2f xhi; xhi.x=x4[jj].z; xhi.y=x4[jj].w;
            acc[2*ih+0][jj] = pkfma(zalo, xlo, acc[2*ih+0][jj]);
            acc[2*ih+0][jj] = pkfma(zahi, xhi, acc[2*ih+0][jj]);
            acc[2*ih+1][jj] = pkfma(zblo, xlo, acc[2*ih+1][jj]);
            acc[2*ih+1][jj] = pkfma(zbhi, xhi, acc[2*ih+1][jj]);
          }
        }
      }
#pragma unroll
      for (int ii=0;ii<4;ii++) {
#pragma unroll
        for (int jj=0;jj<4;jj++) {
          float s = (acc[ii][jj].x + acc[ii][jj].y) * 0.125f;
          S[ii] += __expf(s);
        }
      }
    }
#pragma unroll
    for (int ii=0;ii<4;ii++) {
      S[ii] += __shfl_xor(S[ii], 1);
      S[ii] += __shfl_xor(S[ii], 2);
    }
    if (lj == 0) {
#pragma unroll
      for (int ii=0;ii<4;ii++) exS[mh*256 + 64*nb + 16*ii + li] = S[ii];
    }
  }
  // diag half-dot: z[n][col0..]*x[n][col0..]
  float dh = 0.f;
#pragma unroll
  for (int q=0;q<8;q++) {
    float4 zv = *(const float4*)&zs[n*68 + col0 + 4*q];
    float4 xv = *(const float4*)&xs[n*68 + col0 + 4*q];
    dh = fmaf(zv.x, xv.x, dh);
    dh = fmaf(zv.y, xv.y, dh);
    dh = fmaf(zv.z, xv.z, dh);
    dh = fmaf(zv.w, xv.w, dh);
  }
  exD[h*256 + n] = dh;
  __syncthreads();
  if (h == 0) {
    float Ssum = exS[n] + exS[256 + n];
    float diag = (exD[n] + exD[256 + n]) * 0.125f;
    anng[(size_t)bt*256 + n] = __expf(diag) / Ssum;
  }
}

// ---------------- attention part B: o1 = x + relu(ann*(xWv+bv)); v = dense+norm ----------------
__global__ __launch_bounds__(512,1) void attn_apply(
    const float* __restrict__ x1, const float* __restrict__ anng,
    const float* __restrict__ Wv, const float* __restrict__ bv,
    const float* __restrict__ Wd, const float* __restrict__ bd,
    float* __restrict__ vout)
{
  __shared__ float xs[256*68];
  __shared__ float exN[512];
  const int bt  = blockIdx.x;
  const int tid = threadIdx.x;
  const int n = tid & 255, h = tid >> 8, col0 = 32*h;
  const float* xsl = x1 + (size_t)bt*SLICE;

  const float4* xb4 = (const float4*)xsl;
#pragma unroll
  for (int it=0; it<8; it++) {
    int flat4 = it*512 + tid;
    int row = flat4 >> 4, c = flat4 & 15;
    *(float4*)&xs[row*68 + c*4] = xb4[flat4];
  }
  __syncthreads();

  const float ann = anng[(size_t)bt*256 + n];

  // V-projection own col-half, stream x row from LDS; o1own in regs
  float o1own[32];
  {
    v2f va[16];
#pragma unroll
    for (int j=0;j<16;j++) { v2f t; t.x = bv[col0+2*j]; t.y = bv[col0+2*j+1]; va[j] = t; }
    auto vstep = [&](float v_, const float* wrow) {
      v2f xv; xv.x = v_; xv.y = v_;
      const float4* wr = (const float4*)wrow;
#pragma unroll
      for (int qq=0; qq<8; qq++) {
        float4 w4 = wr[qq];
        v2f wlo; wlo.x=w4.x; wlo.y=w4.y;
        v2f whi; whi.x=w4.z; whi.y=w4.w;
        va[2*qq]   = pkfma(xv, wlo, va[2*qq]);
        va[2*qq+1] = pkfma(xv, whi, va[2*qq+1]);
      }
    };
    for (int q=0;q<16;q++) {
      float4 xc = *(const float4*)&xs[n*68 + 4*q];
      const float* wb = Wv + (4*q)*64 + col0;
      vstep(xc.x, wb);
      vstep(xc.y, wb + 64);
      vstep(xc.z, wb + 128);
      vstep(xc.w, wb + 192);
    }
#pragma unroll
    for (int qq=0;qq<8;qq++) {
      float4 xc = *(const float4*)&xs[n*68 + col0 + 4*qq];
      float g0 = ann * za_get(va, 4*qq+0);
      float g1 = ann * za_get(va, 4*qq+1);
      float g2 = ann * za_get(va, 4*qq+2);
      float g3 = ann * za_get(va, 4*qq+3);
      o1own[4*qq+0] = xc.x + (g0 > 0.f ? g0 : 0.f);
      o1own[4*qq+1] = xc.y + (g1 > 0.f ? g1 : 0.f);
      o1own[4*qq+2] = xc.z + (g2 > 0.f ? g2 : 0.f);
      o1own[4*qq+3] = xc.w + (g3 > 0.f ? g3 : 0.f);
    }
  }
  __syncthreads();                   // all V-proj x reads complete
#pragma unroll
  for (int qq=0;qq<8;qq++) {
    float4 t; t.x=o1own[4*qq+0]; t.y=o1own[4*qq+1]; t.z=o1own[4*qq+2]; t.w=o1own[4*qq+3];
    *(float4*)&xs[n*68 + col0 + 4*qq] = t;   // xs now holds o1
  }
  __syncthreads();

  // dense projection own col-half, stream o1 row from LDS
  float dd[32];
  {
    v2f da[16];
#pragma unroll
    for (int j=0;j<16;j++) { v2f t; t.x = bd[col0+2*j]; t.y = bd[col0+2*j+1]; da[j] = t; }
    auto dstep = [&](float v_, const float* wrow) {
      v2f xv; xv.x = v_; xv.y = v_;
      const float4* wr = (const float4*)wrow;
#pragma unroll
      for (int qq=0; qq<8; qq++) {
        float4 w4 = wr[qq];
        v2f wlo; wlo.x=w4.x; wlo.y=w4.y;
        v2f whi; whi.x=w4.z; whi.y=w4.w;
        da[2*qq]   = pkfma(xv, wlo, da[2*qq]);
        da[2*qq+1] = pkfma(xv, whi, da[2*qq+1]);
      }
    };
    for (int q=0;q<16;q++) {
      float4 o4 = *(const float4*)&xs[n*68 + 4*q];
      const float* wb = Wd + (4*q)*64 + col0;
      dstep(o4.x, wb);
      dstep(o4.y, wb + 64);
      dstep(o4.z, wb + 128);
      dstep(o4.w, wb + 192);
    }
#pragma unroll
    for (int o=0;o<32;o++) dd[o] = za_get(da, o);
  }
  float nh = 0.f;
#pragma unroll
  for (int o=0;o<32;o++) nh = fmaxf(nh, fabsf(dd[o]));
  exN[h*256 + n] = nh;
  __syncthreads();                   // also fences all dense o1-reads of xs
  const float nrm = fmaxf(exN[n], exN[256 + n]);
#pragma unroll
  for (int qq=0;qq<8;qq++) {
    float4 t;
    t.x = 0.5f*(dd[4*qq+0]/nrm + 1.f);
    t.y = 0.5f*(dd[4*qq+1]/nrm + 1.f);
    t.z = 0.5f*(dd[4*qq+2]/nrm + 1.f);
    t.w = 0.5f*(dd[4*qq+3]/nrm + 1.f);
    *(float4*)&xs[n*68 + col0 + 4*qq] = t;   // xs now holds v
  }
  __syncthreads();
  float4* ob4 = (float4*)(vout + (size_t)bt*SLICE);
#pragma unroll
  for (int it=0; it<8; it++) {
    int flat4 = it*512 + tid;
    int row = flat4 >> 4, c = flat4 & 15;
    ob4[flat4] = *(const float4*)&xs[row*68 + c*4];
  }
}

// ---------------- radix-select histograms (values are non-negative floats) ----------------
template<int LEVEL>
__global__ __launch_bounds__(256) void hist_kernel(
    const float* __restrict__ v, unsigned* __restrict__ ghist,
    const unsigned* __restrict__ pfx)
{
  __shared__ unsigned hh[4096];
  const int batch = blockIdx.x >> 5, chunk = blockIdx.x & 31;
  const int tid = threadIdx.x;
#pragma unroll
  for (int k=0;k<16;k++) hh[k*256+tid] = 0u;
  __syncthreads();
  const unsigned p = pfx ? pfx[batch] : 0u;
  const float4* vb = (const float4*)(v + (size_t)batch*(TT*SLICE)) + chunk*8192 + tid;
  for (int k=0;k<32;k++) {
    float4 q = vb[k*256];
    float e[4] = {q.x,q.y,q.z,q.w};
#pragma unroll
    for (int j=0;j<4;j++) {
      unsigned u = __float_as_uint(e[j]);
      if (LEVEL==1) atomicAdd(&hh[u>>20], 1u);
      else if ((u>>20)==p) atomicAdd(&hh[(u>>8)&0xFFFu], 1u);
    }
  }
  __syncthreads();
  unsigned* gh = ghist + batch*4096;
#pragma unroll
  for (int k=0;k<16;k++) { unsigned c = hh[k*256+tid]; if (c) atomicAdd(&gh[k*256+tid], c); }
}

__global__ __launch_bounds__(256) void hist8_kernel(
    const float* __restrict__ v, unsigned* __restrict__ ghist,
    const unsigned* __restrict__ pfx)
{
  __shared__ unsigned hh[256];
  const int batch = blockIdx.x >> 5, chunk = blockIdx.x & 31;
  const int tid = threadIdx.x;
  hh[tid] = 0u;
  __syncthreads();
  const unsigned p = pfx[batch];
  const float4* vb = (const float4*)(v + (size_t)batch*(TT*SLICE)) + chunk*8192 + tid;
  for (int k=0;k<32;k++) {
    float4 q = vb[k*256];
    float e[4] = {q.x,q.y,q.z,q.w};
#pragma unroll
    for (int j=0;j<4;j++) {
      unsigned u = __float_as_uint(e[j]);
      if ((u>>8)==p) atomicAdd(&hh[u & 255u], 1u);
    }
  }
  __syncthreads();
  unsigned c = hh[tid];
  if (c) atomicAdd(&ghist[batch*256+tid], c);
}

// ---------------- find bin containing the rank (block scan per batch) ----------------
template<int PER>
__global__ __launch_bounds__(256) void find_kernel(
    const unsigned* __restrict__ hist,
    const unsigned* __restrict__ rank_in, const unsigned* __restrict__ pfx_in,
    int pfx_shift, unsigned* __restrict__ pfx_out, unsigned* __restrict__ rank_out,
    float* __restrict__ mu, int final_level)
{
  __shared__ unsigned csum[256];
  const int batch = blockIdx.x;
  const int tid = threadIdx.x;
  const unsigned* hb = hist + batch*(PER*256);
  unsigned loc[PER];
  unsigned s = 0;
#pragma unroll
  for (int q=0;q<PER;q++) { loc[q] = hb[tid*PER+q]; s += loc[q]; }
  csum[tid] = s;
  __syncthreads();
  for (int off=1; off<256; off<<=1) {
    unsigned vv = csum[tid];
    unsigned ad = (tid >= off) ? csum[tid-off] : 0u;
    __syncthreads();
    csum[tid] = vv + ad;
    __syncthreads();
  }
  const unsigned rank = rank_in ? rank_in[batch] : RANK0;
  const unsigned excl = csum[tid] - s;
  if (rank >= excl && rank < excl + s) {
    unsigned r = rank - excl;
    int bin = 0;
#pragma unroll
    for (int q=0;q<PER;q++) {
      if (r < loc[q]) { bin = tid*PER + q; break; }
      r -= loc[q];
    }
    unsigned pf = pfx_in ? pfx_in[batch] : 0u;
    unsigned np = (pf << pfx_shift) | (unsigned)bin;
    if (final_level) { mu[batch] = __uint_as_float(np); }
    else { pfx_out[batch] = np; rank_out[batch] = r; }
  }
}

// ---------------- sigmoid + STE mask + predictor, per (b,t) ----------------
__global__ __launch_bounds__(256,2) void final_kernel(
    const float* __restrict__ v, const float* __restrict__ mu,
    const float* __restrict__ Wp, const float* __restrict__ bp,
    float* __restrict__ pred, float* __restrict__ mask)
{
  __shared__ float sl[NNODES*68];
  const int bt = blockIdx.x;
  const int b = bt >> 6;
  const int tid = threadIdx.x;
  const float4* vb4 = (const float4*)(v + (size_t)bt*SLICE);
#pragma unroll
  for (int it=0; it<16; it++) {
    int flat4 = it*256 + tid;
    int n = flat4 >> 4, f4 = (flat4 & 15) << 2;
    *(float4*)&sl[n*68 + f4] = vb4[flat4];
  }
  __syncthreads();
  const float muv = mu[b];
  float srow[64];                    // masked row; compile-time indexed only
#pragma unroll
  for (int q=0;q<16;q++) {
    float4 vv = *(const float4*)&sl[tid*68 + q*4];
    float e0 = 1.f/(1.f + expf(-(vv.x - muv)));
    float e1 = 1.f/(1.f + expf(-(vv.y - muv)));
    float e2 = 1.f/(1.f + expf(-(vv.z - muv)));
    float e3 = 1.f/(1.f + expf(-(vv.w - muv)));
    float m0 = rintf(e0), m1 = rintf(e1), m2 = rintf(e2), m3 = rintf(e3);
    srow[q*4+0] = e0*m0; srow[q*4+1] = e1*m1; srow[q*4+2] = e2*m2; srow[q*4+3] = e3*m3;
    float4 w; w.x=m0; w.y=m1; w.z=m2; w.w=m3;
    *(float4*)&sl[tid*68 + q*4] = w;
  }
  __syncthreads();
  float4* mb4 = (float4*)(mask + (size_t)bt*SLICE);
#pragma unroll
  for (int it=0; it<16; it++) {
    int flat4 = it*256 + tid;
    int n = flat4 >> 4, f4 = (flat4 & 15) << 2;
    mb4[flat4] = *(const float4*)&sl[n*68 + f4];
  }
  __syncthreads();                   // mask stage-out complete; sl rows free
  // write masked row to own sl row, then dense from LDS (no dynamic reg indexing)
#pragma unroll
  for (int q=0;q<16;q++) {
    float4 t; t.x=srow[q*4+0]; t.y=srow[q*4+1]; t.z=srow[q*4+2]; t.w=srow[q*4+3];
    *(float4*)&sl[tid*68 + q*4] = t;
  }
  float acc[64];
#pragma unroll
  for (int o=0;o<64;o++) acc[o]=0.f;
  auto pstep = [&](float sv, const float* wrow) {
    const float4* wr = (const float4*)wrow;
#pragma unroll
    for (int o=0;o<16;o++) {
      float4 w4 = wr[o];
      acc[4*o+0] = fmaf(sv, w4.x, acc[4*o+0]);
      acc[4*o+1] = fmaf(sv, w4.y, acc[4*o+1]);
      acc[4*o+2] = fmaf(sv, w4.z, acc[4*o+2]);
      acc[4*o+3] = fmaf(sv, w4.w, acc[4*o+3]);
    }
  };
  for (int q=0;q<16;q++) {           // own-row write -> own-row read: no barrier needed
    float4 s4 = *(const float4*)&sl[tid*68 + 4*q];
    const float* wb = Wp + (4*q)*64;
    pstep(s4.x, wb);
    pstep(s4.y, wb + 64);
    pstep(s4.z, wb + 128);
    pstep(s4.w, wb + 192);
  }
  __syncthreads();                   // everyone done reading own masked row
#pragma unroll
  for (int q=0;q<16;q++) {
    float4 w;
    w.x = acc[q*4+0]+bp[q*4+0]; w.y = acc[q*4+1]+bp[q*4+1];
    w.z = acc[q*4+2]+bp[q*4+2]; w.w = acc[q*4+3]+bp[q*4+3];
    *(float4*)&sl[tid*68 + q*4] = w;
  }
  __syncthreads();
  float4* pb4 = (float4*)(pred + (size_t)bt*SLICE);
#pragma unroll
  for (int it=0; it<16; it++) {
    int flat4 = it*256 + tid;
    int n = flat4 >> 4, f4 = (flat4 & 15) << 2;
    pb4[flat4] = *(const float4*)&sl[n*68 + f4];
  }
}

extern "C" void kernel_launch(void* const* d_in, const int* in_sizes, int n_in,
                              void* d_out, int out_size, void* d_ws, size_t ws_size,
                              hipStream_t stream) {
  const float* x   = (const float*)d_in[0];
  const float* Wc1 = (const float*)d_in[1];  const float* bc1 = (const float*)d_in[2];
  const float* Wc2 = (const float*)d_in[3];  const float* bc2 = (const float*)d_in[4];
  const float* Wc3 = (const float*)d_in[5];  const float* bc3 = (const float*)d_in[6];
  const float* Wq  = (const float*)d_in[7];  const float* bq  = (const float*)d_in[8];
  const float* Wk  = (const float*)d_in[9];
  const float* Wv  = (const float*)d_in[11]; const float* bv  = (const float*)d_in[12];
  const float* Wd  = (const float*)d_in[13]; const float* bd  = (const float*)d_in[14];
  const float* Wp  = (const float*)d_in[15]; const float* bp  = (const float*)d_in[16];

  float* pred = (float*)d_out;       // also holds pre-sigmoid v, overwritten in place
  float* mask = pred + NTOT;         // also holds conv output x1, overwritten in place

  unsigned* hist1 = (unsigned*)d_ws;           // 32*4096
  unsigned* hist2 = hist1 + 32*4096;           // 32*4096
  unsigned* hist3 = hist2 + 32*4096;           // 32*256
  unsigned* pfx1  = hist3 + 32*256;
  unsigned* rank1 = pfx1 + 32;
  unsigned* pfx2  = rank1 + 32;
  unsigned* rank2 = pfx2 + 32;
  float*    muv   = (float*)(rank2 + 32);
  float*    Wcomb = muv + 32;                  // 7*64*64
  float*    bcomb = Wcomb + 7*64*64;           // 64
  float*    Wqk   = bcomb + 64;                // 64*64
  float*    zbv   = Wqk + 64*64;               // 64
  float*    anng  = zbv + 64;                  // BB*TT*256 floats (2 MB)

  hipMemsetAsync(d_ws, 0, (size_t)(32*4096*2 + 32*256)*sizeof(unsigned), stream);
  combine_w<<<112, 256, 0, stream>>>(Wc1,bc1,Wc2,bc2,Wc3,bc3,Wcomb,bcomb);
  combine_qk<<<17, 256, 0, stream>>>(Wq,bq,Wk,Wqk,zbv);
  conv_kernel<<<BB*NNODES, 256, 0, stream>>>(x, Wcomb, bcomb, mask /*x1*/);
  attn_scores<<<BB*TT, 512, 0, stream>>>(mask /*x1*/, Wqk, zbv, anng);
  attn_apply<<<BB*TT, 512, 0, stream>>>(mask /*x1*/, anng, Wv,bv,Wd,bd, pred /*v*/);
  hist_kernel<1><<<1024, 256, 0, stream>>>(pred, hist1, nullptr);
  find_kernel<16><<<32, 256, 0, stream>>>(hist1, nullptr, nullptr, 0, pfx1, rank1, nullptr, 0);
  hist_kernel<2><<<1024, 256, 0, stream>>>(pred, hist2, pfx1);
  find_kernel<16><<<32, 256, 0, stream>>>(hist2, rank1, pfx1, 12, pfx2, rank2, nullptr, 0);
  hist8_kernel<<<1024, 256, 0, stream>>>(pred, hist3, pfx2);
  find_kernel<1><<<32, 256, 0, stream>>>(hist3, rank2, pfx2, 8, nullptr, nullptr, muv, 1);
  final_kernel<<<BB*TT, 256, 0, stream>>>(pred /*v*/, muv, Wp, bp, pred, mask);
}

// Round 10
// 1602.813 us; speedup vs baseline: 5.2765x; 1.0651x over previous
//
#include <hip/hip_runtime.h>
#include <math.h>

#define BB 32
#define TT 64
#define NNODES 256
#define FDIM 64
#define SLICE (NNODES*FDIM)          // 16384 floats per (b,t) slice
#define NTOT (BB*TT*NNODES*FDIM)     // 33554432
#define RANK0 838860u                // ascending order-statistic index: T*N*F - k - 1, k=209715

typedef float v2f __attribute__((ext_vector_type(2)));
__device__ __forceinline__ v2f pkfma(v2f a, v2f b, v2f c) {
#if __has_builtin(__builtin_elementwise_fma)
  return __builtin_elementwise_fma(a, b, c);
#else
  v2f r; r.x = fmaf(a.x,b.x,c.x); r.y = fmaf(a.y,b.y,c.y); return r;
#endif
}
__device__ __forceinline__ float za_get(const v2f* a, int o) {
  return (o & 1) ? a[o>>1].y : a[o>>1].x;
}
#define SCHED_FENCE() __builtin_amdgcn_sched_barrier(0)

// ---------------- weight combine: 7 effective taps (-3..+3) ----------------
__global__ __launch_bounds__(256) void combine_w(
    const float* __restrict__ Wc1, const float* __restrict__ bc1,
    const float* __restrict__ Wc2, const float* __restrict__ bc2,
    const float* __restrict__ Wc3, const float* __restrict__ bc3,
    float* __restrict__ Wcomb, float* __restrict__ bcomb)
{
  const int FF2 = FDIM*FDIM;
  int gid = blockIdx.x*256 + threadIdx.x;
  if (gid < 7*FF2) {
    int j = gid / FF2, r = gid % FF2;
    float v;
    switch (j) {
      case 0: v = Wc3[r]; break;                                   // offset -3
      case 1: v = Wc2[r]; break;                                   // offset -2
      case 2: v = Wc1[r]; break;                                   // offset -1
      case 3: v = Wc1[FF2+r] + Wc2[FF2+r] + Wc3[FF2+r]; break;     // offset  0
      case 4: v = Wc1[2*FF2+r]; break;                             // offset +1
      case 5: v = Wc2[2*FF2+r]; break;                             // offset +2
      default: v = Wc3[2*FF2+r]; break;                            // offset +3
    }
    Wcomb[gid] = v;
  }
  if (gid < FDIM) bcomb[gid] = bc1[gid] + bc2[gid] + bc3[gid];
}

// ---------------- fold Q/K projections: Wqk = Wq*Wk^T, zb = bq*Wk^T ----------------
__global__ __launch_bounds__(256) void combine_qk(
    const float* __restrict__ Wq, const float* __restrict__ bq,
    const float* __restrict__ Wk,
    float* __restrict__ Wqk, float* __restrict__ zb)
{
  int gid = blockIdx.x*256 + threadIdx.x;
  if (gid < 4096) {
    int i = gid >> 6, j = gid & 63;
    float a = 0.f;
    for (int o=0;o<64;o++) a = fmaf(Wq[i*64+o], Wk[j*64+o], a);
    Wqk[i*64+j] = a;
  } else if (gid < 4160) {
    int j = gid - 4096;
    float a = 0.f;
    for (int o=0;o<64;o++) a = fmaf(bq[o], Wk[j*64+o], a);
    zb[j] = a;
  }
}

// ---------------- dilated conv block + residual, per (b,n) slice ----------------
__global__ __launch_bounds__(256,4) void conv_kernel(
    const float* __restrict__ x, const float* __restrict__ Wcomb,
    const float* __restrict__ bcomb, float* __restrict__ x1)
{
  __shared__ float xs[64*72];        // [f][t+4], t in [-4,68), zero-padded
  const int bn = blockIdx.x; const int b = bn >> 8; const int n = bn & 255;
  const int tid = threadIdx.x;
#pragma unroll
  for (int k=0;k<18;k++) xs[k*256+tid] = 0.f;
  __syncthreads();
  const float* xbase = x + ((size_t)b*TT)*SLICE + n*FDIM;
#pragma unroll
  for (int it=0; it<4; it++) {
    int flat4 = it*256 + tid;
    int t = flat4 >> 4, f4 = (flat4 & 15) << 2;
    float4 v = *(const float4*)(xbase + (size_t)t*SLICE + f4);
    xs[(f4+0)*72 + t+4] = v.x;
    xs[(f4+1)*72 + t+4] = v.y;
    xs[(f4+2)*72 + t+4] = v.z;
    xs[(f4+3)*72 + t+4] = v.w;
  }
  __syncthreads();
  const int o = tid & 63;            // lane -> output feature
  const int tb = (tid >> 6) << 4;    // wave -> 16-step t range (wave-uniform)
  float acc[16];
  const float bco = bcomb[o];
#pragma unroll
  for (int k=0;k<16;k++) acc[k] = bco;
  for (int i=0;i<FDIM;i++) {
    float xr[24];
#pragma unroll
    for (int q=0;q<6;q++) {
      float4 v = *(const float4*)&xs[i*72 + tb + q*4];
      xr[q*4+0]=v.x; xr[q*4+1]=v.y; xr[q*4+2]=v.z; xr[q*4+3]=v.w;
    }
#pragma unroll
    for (int j=0;j<7;j++) {
      float w = Wcomb[(j*FDIM+i)*FDIM + o];
#pragma unroll
      for (int k=0;k<16;k++) acc[k] = fmaf(xr[k+j+1], w, acc[k]);
    }
  }
  float* obase = x1 + ((size_t)b*TT)*SLICE + n*FDIM + o;
#pragma unroll
  for (int k=0;k<16;k++) {
    int t = tb + k;
    float c = acc[k];
    float outv = xs[o*72 + t+4] + (c > 0.f ? c : 0.f);
    obase[(size_t)t*SLICE] = outv;
  }
}

// ---------------- attention part A: scores + softmax -> ann[bt][n] ----------------
// R10: cap scheduler lookahead. Score kc-loop unroll 2 (16 in-flight ds_read dests
// = 64 VGPR + 32 acc fits the 128-VGPR allocation); sched_barrier(0) between
// projection steps (8 float4 weight loads per batch). The ~380 MB/dispatch phantom
// WRITE in R7-R9 was hoisted-load live-range spill, not source-level arrays.
__global__ __launch_bounds__(512,1) void attn_scores(
    const float* __restrict__ x1,
    const float* __restrict__ Wqk, const float* __restrict__ zb,
    float* __restrict__ anng)
{
  __shared__ float lds[2*256*68 + 1024];
  float* xs  = lds;                  // [256][68]
  float* zs  = lds + 256*68;         // [256][68]
  float* exS = lds + 2*256*68;       // [2][256] denom halves
  float* exD = exS + 512;            // [2][256] diag-dot halves
  const int bt  = blockIdx.x;
  const int tid = threadIdx.x;
  const int w = tid >> 6, l = tid & 63;
  const int nb = w & 3, mh = w >> 2;
  const float* xsl = x1 + (size_t)bt*SLICE;

  // stage-in x
  const float4* xb4 = (const float4*)xsl;
#pragma unroll
  for (int it=0; it<8; it++) {
    int flat4 = it*512 + tid;
    int row = flat4 >> 4, c = flat4 & 15;
    *(float4*)&xs[row*68 + c*4] = xb4[flat4];
  }
  __syncthreads();

  // z-projection: thread (n = tid&255, h = tid>>8) computes z[n][32h..+32)
  const int n = tid & 255, h = tid >> 8, col0 = 32*h;
  {
    v2f za[16];
#pragma unroll
    for (int j=0;j<16;j++) { v2f t; t.x = zb[col0+2*j]; t.y = zb[col0+2*j+1]; za[j] = t; }
    auto zstep = [&](float v_, const float* wrow) {
      v2f xv; xv.x = v_; xv.y = v_;
      const float4* wr = (const float4*)wrow;
#pragma unroll
      for (int qq=0; qq<8; qq++) {
        float4 w4 = wr[qq];
        v2f wlo; wlo.x=w4.x; wlo.y=w4.y;
        v2f whi; whi.x=w4.z; whi.y=w4.w;
        za[2*qq]   = pkfma(xv, wlo, za[2*qq]);
        za[2*qq+1] = pkfma(xv, whi, za[2*qq+1]);
      }
    };
    for (int q=0;q<16;q++) {
      float4 xc = *(const float4*)&xs[n*68 + 4*q];
      const float* wb = Wqk + (4*q)*64 + col0;
      zstep(xc.x, wb);        SCHED_FENCE();
      zstep(xc.y, wb + 64);   SCHED_FENCE();
      zstep(xc.z, wb + 128);  SCHED_FENCE();
      zstep(xc.w, wb + 192);  SCHED_FENCE();
    }
#pragma unroll
    for (int qq=0;qq<8;qq++) {
      float4 t; t.x=za[2*qq].x; t.y=za[2*qq].y; t.z=za[2*qq+1].x; t.w=za[2*qq+1].y;
      *(float4*)&zs[n*68 + col0 + 4*qq] = t;
    }
  }
  __syncthreads();

  // score sweep, exp-sum only (diag handled after)
  float S[4] = {0,0,0,0};
  {
    const int li = l >> 2, lj = l & 3;
    const float* zrow = &zs[(64*nb + li)*68];
    for (int mt=0; mt<8; mt++) {
      const float* xrow = &xs[(128*mh + 16*mt + lj)*68];
      v2f acc[4][4];
#pragma unroll
      for (int ii=0;ii<4;ii++)
#pragma unroll
        for (int jj=0;jj<4;jj++) { acc[ii][jj].x = 0.f; acc[ii][jj].y = 0.f; }
#pragma unroll 2
      for (int kc=0; kc<16; kc++) {
        float4 x4[4];
#pragma unroll
        for (int jj=0;jj<4;jj++) x4[jj] = *(const float4*)(xrow + jj*(4*68) + kc*4);
#pragma unroll
        for (int ih=0; ih<2; ih++) {
          float4 z4a = *(const float4*)(zrow + (2*ih+0)*(16*68) + kc*4);
          float4 z4b = *(const float4*)(zrow + (2*ih+1)*(16*68) + kc*4);
          v2f zalo; zalo.x=z4a.x; zalo.y=z4a.y;
          v2f zahi; zahi.x=z4a.z; zahi.y=z4a.w;
          v2f zblo; zblo.x=z4b.x; zblo.y=z4b.y;
          v2f zbhi; zbhi.x=z4b.z; zbhi.y=z4b.w;
#pragma unroll
          for (int jj=0;jj<4;jj++) {
            v2f xlo; xlo.x=x4[jj].x; xlo.y=x4[jj].y;
            v2f xhi; xhi.x=x4[jj].z; xhi.y=x4[jj].w;
            acc[2*ih+0][jj] = pkfma(zalo, xlo, acc[2*ih+0][jj]);
            acc[2*ih+0][jj] = pkfma(zahi, xhi, acc[2*ih+0][jj]);
            acc[2*ih+1][jj] = pkfma(zblo, xlo, acc[2*ih+1][jj]);
            acc[2*ih+1][jj] = pkfma(zbhi, xhi, acc[2*ih+1][jj]);
          }
        }
      }
#pragma unroll
      for (int ii=0;ii<4;ii++) {
#pragma unroll
        for (int jj=0;jj<4;jj++) {
          float s = (acc[ii][jj].x + acc[ii][jj].y) * 0.125f;
          S[ii] += __expf(s);
        }
      }
    }
#pragma unroll
    for (int ii=0;ii<4;ii++) {
      S[ii] += __shfl_xor(S[ii], 1);
      S[ii] += __shfl_xor(S[ii], 2);
    }
    if (lj == 0) {
#pragma unroll
      for (int ii=0;ii<4;ii++) exS[mh*256 + 64*nb + 16*ii + li] = S[ii];
    }
  }
  // diag half-dot: z[n][col0..]*x[n][col0..]
  float dh = 0.f;
#pragma unroll
  for (int q=0;q<8;q++) {
    float4 zv = *(const float4*)&zs[n*68 + col0 + 4*q];
    float4 xv = *(const float4*)&xs[n*68 + col0 + 4*q];
    dh = fmaf(zv.x, xv.x, dh);
    dh = fmaf(zv.y, xv.y, dh);
    dh = fmaf(zv.z, xv.z, dh);
    dh = fmaf(zv.w, xv.w, dh);
  }
  exD[h*256 + n] = dh;
  __syncthreads();
  if (h == 0) {
    float Ssum = exS[n] + exS[256 + n];
    float diag = (exD[n] + exD[256 + n]) * 0.125f;
    anng[(size_t)bt*256 + n] = __expf(diag) / Ssum;
  }
}

// ---------------- attention part B: o1 = x + relu(ann*(xWv+bv)); v = dense+norm ----------------
__global__ __launch_bounds__(512,1) void attn_apply(
    const float* __restrict__ x1, const float* __restrict__ anng,
    const float* __restrict__ Wv, const float* __restrict__ bv,
    const float* __restrict__ Wd, const float* __restrict__ bd,
    float* __restrict__ vout)
{
  __shared__ float xs[256*68];
  __shared__ float exN[512];
  const int bt  = blockIdx.x;
  const int tid = threadIdx.x;
  const int n = tid & 255, h = tid >> 8, col0 = 32*h;
  const float* xsl = x1 + (size_t)bt*SLICE;

  const float4* xb4 = (const float4*)xsl;
#pragma unroll
  for (int it=0; it<8; it++) {
    int flat4 = it*512 + tid;
    int row = flat4 >> 4, c = flat4 & 15;
    *(float4*)&xs[row*68 + c*4] = xb4[flat4];
  }
  __syncthreads();

  const float ann = anng[(size_t)bt*256 + n];

  // V-projection own col-half, stream x row from LDS; o1own in regs
  float o1own[32];
  {
    v2f va[16];
#pragma unroll
    for (int j=0;j<16;j++) { v2f t; t.x = bv[col0+2*j]; t.y = bv[col0+2*j+1]; va[j] = t; }
    auto vstep = [&](float v_, const float* wrow) {
      v2f xv; xv.x = v_; xv.y = v_;
      const float4* wr = (const float4*)wrow;
#pragma unroll
      for (int qq=0; qq<8; qq++) {
        float4 w4 = wr[qq];
        v2f wlo; wlo.x=w4.x; wlo.y=w4.y;
        v2f whi; whi.x=w4.z; whi.y=w4.w;
        va[2*qq]   = pkfma(xv, wlo, va[2*qq]);
        va[2*qq+1] = pkfma(xv, whi, va[2*qq+1]);
      }
    };
    for (int q=0;q<16;q++) {
      float4 xc = *(const float4*)&xs[n*68 + 4*q];
      const float* wb = Wv + (4*q)*64 + col0;
      vstep(xc.x, wb);        SCHED_FENCE();
      vstep(xc.y, wb + 64);   SCHED_FENCE();
      vstep(xc.z, wb + 128);  SCHED_FENCE();
      vstep(xc.w, wb + 192);  SCHED_FENCE();
    }
#pragma unroll
    for (int qq=0;qq<8;qq++) {
      float4 xc = *(const float4*)&xs[n*68 + col0 + 4*qq];
      float g0 = ann * za_get(va, 4*qq+0);
      float g1 = ann * za_get(va, 4*qq+1);
      float g2 = ann * za_get(va, 4*qq+2);
      float g3 = ann * za_get(va, 4*qq+3);
      o1own[4*qq+0] = xc.x + (g0 > 0.f ? g0 : 0.f);
      o1own[4*qq+1] = xc.y + (g1 > 0.f ? g1 : 0.f);
      o1own[4*qq+2] = xc.z + (g2 > 0.f ? g2 : 0.f);
      o1own[4*qq+3] = xc.w + (g3 > 0.f ? g3 : 0.f);
    }
  }
  __syncthreads();                   // all V-proj x reads complete
#pragma unroll
  for (int qq=0;qq<8;qq++) {
    float4 t; t.x=o1own[4*qq+0]; t.y=o1own[4*qq+1]; t.z=o1own[4*qq+2]; t.w=o1own[4*qq+3];
    *(float4*)&xs[n*68 + col0 + 4*qq] = t;   // xs now holds o1
  }
  __syncthreads();

  // dense projection own col-half, stream o1 row from LDS
  float dd[32];
  {
    v2f da[16];
#pragma unroll
    for (int j=0;j<16;j++) { v2f t; t.x = bd[col0+2*j]; t.y = bd[col0+2*j+1]; da[j] = t; }
    auto dstep = [&](float v_, const float* wrow) {
      v2f xv; xv.x = v_; xv.y = v_;
      const float4* wr = (const float4*)wrow;
#pragma unroll
      for (int qq=0; qq<8; qq++) {
        float4 w4 = wr[qq];
        v2f wlo; wlo.x=w4.x; wlo.y=w4.y;
        v2f whi; whi.x=w4.z; whi.y=w4.w;
        da[2*qq]   = pkfma(xv, wlo, da[2*qq]);
        da[2*qq+1] = pkfma(xv, whi, da[2*qq+1]);
      }
    };
    for (int q=0;q<16;q++) {
      float4 o4 = *(const float4*)&xs[n*68 + 4*q];
      const float* wb = Wd + (4*q)*64 + col0;
      dstep(o4.x, wb);        SCHED_FENCE();
      dstep(o4.y, wb + 64);   SCHED_FENCE();
      dstep(o4.z, wb + 128);  SCHED_FENCE();
      dstep(o4.w, wb + 192);  SCHED_FENCE();
    }
#pragma unroll
    for (int o=0;o<32;o++) dd[o] = za_get(da, o);
  }
  float nh = 0.f;
#pragma unroll
  for (int o=0;o<32;o++) nh = fmaxf(nh, fabsf(dd[o]));
  exN[h*256 + n] = nh;
  __syncthreads();                   // also fences all dense o1-reads of xs
  const float nrm = fmaxf(exN[n], exN[256 + n]);
#pragma unroll
  for (int qq=0;qq<8;qq++) {
    float4 t;
    t.x = 0.5f*(dd[4*qq+0]/nrm + 1.f);
    t.y = 0.5f*(dd[4*qq+1]/nrm + 1.f);
    t.z = 0.5f*(dd[4*qq+2]/nrm + 1.f);
    t.w = 0.5f*(dd[4*qq+3]/nrm + 1.f);
    *(float4*)&xs[n*68 + col0 + 4*qq] = t;   // xs now holds v
  }
  __syncthreads();
  float4* ob4 = (float4*)(vout + (size_t)bt*SLICE);
#pragma unroll
  for (int it=0; it<8; it++) {
    int flat4 = it*512 + tid;
    int row = flat4 >> 4, c = flat4 & 15;
    ob4[flat4] = *(const float4*)&xs[row*68 + c*4];
  }
}

// ---------------- radix-select histograms (values are non-negative floats) ----------------
template<int LEVEL>
__global__ __launch_bounds__(256) void hist_kernel(
    const float* __restrict__ v, unsigned* __restrict__ ghist,
    const unsigned* __restrict__ pfx)
{
  __shared__ unsigned hh[4096];
  const int batch = blockIdx.x >> 5, chunk = blockIdx.x & 31;
  const int tid = threadIdx.x;
#pragma unroll
  for (int k=0;k<16;k++) hh[k*256+tid] = 0u;
  __syncthreads();
  const unsigned p = pfx ? pfx[batch] : 0u;
  const float4* vb = (const float4*)(v + (size_t)batch*(TT*SLICE)) + chunk*8192 + tid;
  for (int k=0;k<32;k++) {
    float4 q = vb[k*256];
    float e[4] = {q.x,q.y,q.z,q.w};
#pragma unroll
    for (int j=0;j<4;j++) {
      unsigned u = __float_as_uint(e[j]);
      if (LEVEL==1) atomicAdd(&hh[u>>20], 1u);
      else if ((u>>20)==p) atomicAdd(&hh[(u>>8)&0xFFFu], 1u);
    }
  }
  __syncthreads();
  unsigned* gh = ghist + batch*4096;
#pragma unroll
  for (int k=0;k<16;k++) { unsigned c = hh[k*256+tid]; if (c) atomicAdd(&gh[k*256+tid], c); }
}

__global__ __launch_bounds__(256) void hist8_kernel(
    const float* __restrict__ v, unsigned* __restrict__ ghist,
    const unsigned* __restrict__ pfx)
{
  __shared__ unsigned hh[256];
  const int batch = blockIdx.x >> 5, chunk = blockIdx.x & 31;
  const int tid = threadIdx.x;
  hh[tid] = 0u;
  __syncthreads();
  const unsigned p = pfx[batch];
  const float4* vb = (const float4*)(v + (size_t)batch*(TT*SLICE)) + chunk*8192 + tid;
  for (int k=0;k<32;k++) {
    float4 q = vb[k*256];
    float e[4] = {q.x,q.y,q.z,q.w};
#pragma unroll
    for (int j=0;j<4;j++) {
      unsigned u = __float_as_uint(e[j]);
      if ((u>>8)==p) atomicAdd(&hh[u & 255u], 1u);
    }
  }
  __syncthreads();
  unsigned c = hh[tid];
  if (c) atomicAdd(&ghist[batch*256+tid], c);
}

// ---------------- find bin containing the rank (block scan per batch) ----------------
template<int PER>
__global__ __launch_bounds__(256) void find_kernel(
    const unsigned* __restrict__ hist,
    const unsigned* __restrict__ rank_in, const unsigned* __restrict__ pfx_in,
    int pfx_shift, unsigned* __restrict__ pfx_out, unsigned* __restrict__ rank_out,
    float* __restrict__ mu, int final_level)
{
  __shared__ unsigned csum[256];
  const int batch = blockIdx.x;
  const int tid = threadIdx.x;
  const unsigned* hb = hist + batch*(PER*256);
  unsigned loc[PER];
  unsigned s = 0;
#pragma unroll
  for (int q=0;q<PER;q++) { loc[q] = hb[tid*PER+q]; s += loc[q]; }
  csum[tid] = s;
  __syncthreads();
  for (int off=1; off<256; off<<=1) {
    unsigned vv = csum[tid];
    unsigned ad = (tid >= off) ? csum[tid-off] : 0u;
    __syncthreads();
    csum[tid] = vv + ad;
    __syncthreads();
  }
  const unsigned rank = rank_in ? rank_in[batch] : RANK0;
  const unsigned excl = csum[tid] - s;
  if (rank >= excl && rank < excl + s) {
    unsigned r = rank - excl;
    int bin = 0;
#pragma unroll
    for (int q=0;q<PER;q++) {
      if (r < loc[q]) { bin = tid*PER + q; break; }
      r -= loc[q];
    }
    unsigned pf = pfx_in ? pfx_in[batch] : 0u;
    unsigned np = (pf << pfx_shift) | (unsigned)bin;
    if (final_level) { mu[batch] = __uint_as_float(np); }
    else { pfx_out[batch] = np; rank_out[batch] = r; }
  }
}

// ---------------- sigmoid + STE mask + predictor, per (b,t) ----------------
__global__ __launch_bounds__(256,2) void final_kernel(
    const float* __restrict__ v, const float* __restrict__ mu,
    const float* __restrict__ Wp, const float* __restrict__ bp,
    float* __restrict__ pred, float* __restrict__ mask)
{
  __shared__ float sl[NNODES*68];
  const int bt = blockIdx.x;
  const int b = bt >> 6;
  const int tid = threadIdx.x;
  const float4* vb4 = (const float4*)(v + (size_t)bt*SLICE);
#pragma unroll
  for (int it=0; it<16; it++) {
    int flat4 = it*256 + tid;
    int n = flat4 >> 4, f4 = (flat4 & 15) << 2;
    *(float4*)&sl[n*68 + f4] = vb4[flat4];
  }
  __syncthreads();
  const float muv = mu[b];
  float srow[64];                    // masked row; compile-time indexed only
#pragma unroll
  for (int q=0;q<16;q++) {
    float4 vv = *(const float4*)&sl[tid*68 + q*4];
    float e0 = 1.f/(1.f + expf(-(vv.x - muv)));
    float e1 = 1.f/(1.f + expf(-(vv.y - muv)));
    float e2 = 1.f/(1.f + expf(-(vv.z - muv)));
    float e3 = 1.f/(1.f + expf(-(vv.w - muv)));
    float m0 = rintf(e0), m1 = rintf(e1), m2 = rintf(e2), m3 = rintf(e3);
    srow[q*4+0] = e0*m0; srow[q*4+1] = e1*m1; srow[q*4+2] = e2*m2; srow[q*4+3] = e3*m3;
    float4 w; w.x=m0; w.y=m1; w.z=m2; w.w=m3;
    *(float4*)&sl[tid*68 + q*4] = w;
  }
  __syncthreads();
  float4* mb4 = (float4*)(mask + (size_t)bt*SLICE);
#pragma unroll
  for (int it=0; it<16; it++) {
    int flat4 = it*256 + tid;
    int n = flat4 >> 4, f4 = (flat4 & 15) << 2;
    mb4[flat4] = *(const float4*)&sl[n*68 + f4];
  }
  __syncthreads();                   // mask stage-out complete; sl rows free
  // write masked row to own sl row, then dense from LDS (no dynamic reg indexing)
#pragma unroll
  for (int q=0;q<16;q++) {
    float4 t; t.x=srow[q*4+0]; t.y=srow[q*4+1]; t.z=srow[q*4+2]; t.w=srow[q*4+3];
    *(float4*)&sl[tid*68 + q*4] = t;
  }
  float acc[64];
#pragma unroll
  for (int o=0;o<64;o++) acc[o]=0.f;
  auto phalf = [&](float sv, const float* wrow, int half) {
    const float4* wr = (const float4*)wrow + half*8;
#pragma unroll
    for (int o=0;o<8;o++) {
      float4 w4 = wr[o];
      int ob = half*32 + 4*o;
      acc[ob+0] = fmaf(sv, w4.x, acc[ob+0]);
      acc[ob+1] = fmaf(sv, w4.y, acc[ob+1]);
      acc[ob+2] = fmaf(sv, w4.z, acc[ob+2]);
      acc[ob+3] = fmaf(sv, w4.w, acc[ob+3]);
    }
  };
  for (int q=0;q<16;q++) {           // own-row write -> own-row read: no barrier needed
    float4 s4 = *(const float4*)&sl[tid*68 + 4*q];
    const float* wb = Wp + (4*q)*64;
    phalf(s4.x, wb, 0);       SCHED_FENCE();
    phalf(s4.x, wb, 1);       SCHED_FENCE();
    phalf(s4.y, wb + 64, 0);  SCHED_FENCE();
    phalf(s4.y, wb + 64, 1);  SCHED_FENCE();
    phalf(s4.z, wb + 128, 0); SCHED_FENCE();
    phalf(s4.z, wb + 128, 1); SCHED_FENCE();
    phalf(s4.w, wb + 192, 0); SCHED_FENCE();
    phalf(s4.w, wb + 192, 1); SCHED_FENCE();
  }
  __syncthreads();                   // everyone done reading own masked row
#pragma unroll
  for (int q=0;q<16;q++) {
    float4 w;
    w.x = acc[q*4+0]+bp[q*4+0]; w.y = acc[q*4+1]+bp[q*4+1];
    w.z = acc[q*4+2]+bp[q*4+2]; w.w = acc[q*4+3]+bp[q*4+3];
    *(float4*)&sl[tid*68 + q*4] = w;
  }
  __syncthreads();
  float4* pb4 = (float4*)(pred + (size_t)bt*SLICE);
#pragma unroll
  for (int it=0; it<16; it++) {
    int flat4 = it*256 + tid;
    int n = flat4 >> 4, f4 = (flat4 & 15) << 2;
    pb4[flat4] = *(const float4*)&sl[n*68 + f4];
  }
}

extern "C" void kernel_launch(void* const* d_in, const int* in_sizes, int n_in,
                              void* d_out, int out_size, void* d_ws, size_t ws_size,
                              hipStream_t stream) {
  const float* x   = (const float*)d_in[0];
  const float* Wc1 = (const float*)d_in[1];  const float* bc1 = (const float*)d_in[2];
  const float* Wc2 = (const float*)d_in[3];  const float* bc2 = (const float*)d_in[4];
  const float* Wc3 = (const float*)d_in[5];  const float* bc3 = (const float*)d_in[6];
  const float* Wq  = (const float*)d_in[7];  const float* bq  = (const float*)d_in[8];
  const float* Wk  = (const float*)d_in[9];
  const float* Wv  = (const float*)d_in[11]; const float* bv  = (const float*)d_in[12];
  const float* Wd  = (const float*)d_in[13]; const float* bd  = (const float*)d_in[14];
  const float* Wp  = (const float*)d_in[15]; const float* bp  = (const float*)d_in[16];

  float* pred = (float*)d_out;       // also holds pre-sigmoid v, overwritten in place
  float* mask = pred + NTOT;         // also holds conv output x1, overwritten in place

  unsigned* hist1 = (unsigned*)d_ws;           // 32*4096
  unsigned* hist2 = hist1 + 32*4096;           // 32*4096
  unsigned* hist3 = hist2 + 32*4096;           // 32*256
  unsigned* pfx1  = hist3 + 32*256;
  unsigned* rank1 = pfx1 + 32;
  unsigned* pfx2  = rank1 + 32;
  unsigned* rank2 = pfx2 + 32;
  float*    muv   = (float*)(rank2 + 32);
  float*    Wcomb = muv + 32;                  // 7*64*64
  float*    bcomb = Wcomb + 7*64*64;           // 64
  float*    Wqk   = bcomb + 64;                // 64*64
  float*    zbv   = Wqk + 64*64;               // 64
  float*    anng  = zbv + 64;                  // BB*TT*256 floats (2 MB)

  hipMemsetAsync(d_ws, 0, (size_t)(32*4096*2 + 32*256)*sizeof(unsigned), stream);
  combine_w<<<112, 256, 0, stream>>>(Wc1,bc1,Wc2,bc2,Wc3,bc3,Wcomb,bcomb);
  combine_qk<<<17, 256, 0, stream>>>(Wq,bq,Wk,Wqk,zbv);
  conv_kernel<<<BB*NNODES, 256, 0, stream>>>(x, Wcomb, bcomb, mask /*x1*/);
  attn_scores<<<BB*TT, 512, 0, stream>>>(mask /*x1*/, Wqk, zbv, anng);
  attn_apply<<<BB*TT, 512, 0, stream>>>(mask /*x1*/, anng, Wv,bv,Wd,bd, pred /*v*/);
  hist_kernel<1><<<1024, 256, 0, stream>>>(pred, hist1, nullptr);
  find_kernel<16><<<32, 256, 0, stream>>>(hist1, nullptr, nullptr, 0, pfx1, rank1, nullptr, 0);
  hist_kernel<2><<<1024, 256, 0, stream>>>(pred, hist2, pfx1);
  find_kernel<16><<<32, 256, 0, stream>>>(hist2, rank1, pfx1, 12, pfx2, rank2, nullptr, 0);
  hist8_kernel<<<1024, 256, 0, stream>>>(pred, hist3, pfx2);
  find_kernel<1><<<32, 256, 0, stream>>>(hist3, rank2, pfx2, 8, nullptr, nullptr, muv, 1);
  final_kernel<<<BB*TT, 256, 0, stream>>>(pred /*v*/, muv, Wp, bp, pred, mask);
}